// Round 11
// baseline (108.330 us; speedup 1.0000x reference)
//
#include <hip/hip_runtime.h>
#include <hip/hip_bf16.h>
#include <math.h>

#define BB 32
#define LL 2048
#define DD 1024
#define HH 16
#define DHH 64
#define NCK 16         // chunks per batch
#define CH  128        // rows per chunk
#define NT  8          // 16-row tiles per chunk

// ---- ws layout (float offsets) ----
#define WS_R     2048       // 16*1024
#define WS_C     18432      // 64 (16 used)
#define WS_CTX   19008      // 32768
#define WS_Y     51776      // 32768
#define WS_SSUM  84544      // 32*16*16 = 8192
#define WS_PART  92736      // 32*16*16*1024 bf16 = 16 MB

// ---- k_fused dynamic LDS layout (bytes) ----
// G tile buffers: 2 x (16 rows x 1024 e bf16, [4 l][16 e]-subtiled) = 2x32768
//   byte(l,e) = (e>>4)*512 + (l>>2)*128 + (l&3)*32 + (e&15)*2
#define RED_OFF  65536      // 4 waves x 64 lanes x 4 f32 = 4096
#define WT_OFF   69632      // 4 waves x 16 h x 16 l bf16 = 2048
#define SMEM_BYTES 71680

typedef __attribute__((ext_vector_type(8))) short    bf16x8;
typedef __attribute__((ext_vector_type(4))) float    f32x4;
typedef __attribute__((ext_vector_type(2))) unsigned u32x2;
typedef __attribute__((ext_vector_type(4))) unsigned short u16x4;

#define MFMA(a, b, c) __builtin_amdgcn_mfma_f32_16x16x32_bf16(a, b, c, 0, 0, 0)

__device__ __forceinline__ ushort2 pk2(float x, float y) {   // v_cvt_pk_bf16_f32
    __hip_bfloat162 h = __float22bfloat162_rn(make_float2(x, y));
    return *reinterpret_cast<ushort2*>(&h);
}
__device__ __forceinline__ u16x4 pk4(float4 f) {
    ushort2 a = pk2(f.x, f.y), b = pk2(f.z, f.w);
    u16x4 r; r[0] = a.x; r[1] = a.y; r[2] = b.x; r[3] = b.y;
    return r;
}
__device__ __forceinline__ float bf2f(unsigned short u) {
    return __uint_as_float((unsigned)u << 16);
}
__device__ __forceinline__ float wave_sum(float v) {
#pragma unroll
    for (int s = 32; s >= 1; s >>= 1) v += __shfl_xor(v, s, 64);
    return v;
}

// ------- K1: fused q+r: q[h,:] = Wq_h @ LN(sq[pos]) + bq; r,c from q -------
// 64 blocks = (h, quarter); each block redundantly computes its head's q[64].
__global__ void k_qr(const float* __restrict__ sq, const float* __restrict__ qn_w,
                     const float* __restrict__ qn_b, const int* __restrict__ pos,
                     const float* __restrict__ ipw, const float* __restrict__ ipb,
                     float* __restrict__ ws) {
    const int h = blockIdx.x >> 2, qa = blockIdx.x & 3;
    const int t = threadIdx.x, w = t >> 6, lane = t & 63;
    __shared__ float q0s[DD];
    __shared__ float qs[DHH];
    __shared__ float rs[4], rs2[4];
    {   // LN of the single query row (redundant per block; 4 KB, L2-hot)
        const float4 x = ((const float4*)(sq + (size_t)pos[0] * DD))[t];
        float s  = x.x + x.y + x.z + x.w;
        float s2 = x.x * x.x + x.y * x.y + x.z * x.z + x.w * x.w;
        s = wave_sum(s); s2 = wave_sum(s2);
        if (lane == 0) { rs[w] = s; rs2[w] = s2; }
        __syncthreads();
        s  = rs[0] + rs[1] + rs[2] + rs[3];
        s2 = rs2[0] + rs2[1] + rs2[2] + rs2[3];
        const float mu  = s * (1.0f / DD);
        const float var = s2 * (1.0f / DD) - mu * mu;
        const float rstd = rsqrtf(var + 1e-5f);
        const float4 w4 = ((const float4*)qn_w)[t];
        const float4 b4 = ((const float4*)qn_b)[t];
        float4 o;
        o.x = (x.x - mu) * rstd * w4.x + b4.x;
        o.y = (x.y - mu) * rstd * w4.y + b4.y;
        o.z = (x.z - mu) * rstd * w4.z + b4.z;
        o.w = (x.w - mu) * rstd * w4.w + b4.w;
        ((float4*)q0s)[t] = o;
    }
    __syncthreads();
    // q[h, j]: wave w computes j = w*16..w*16+15
    for (int jj = 0; jj < 16; ++jj) {
        const int j = w * 16 + jj;
        const float* row = ipw + (size_t)(h * DHH + j) * DD;
        float acc = 0.f;
#pragma unroll
        for (int it = 0; it < 4; ++it) {
            float4 a = ((const float4*)row)[lane + 64 * it];
            float4 b = ((const float4*)q0s)[lane + 64 * it];
            acc += a.x * b.x + a.y * b.y + a.z * b.z + a.w * b.w;
        }
        acc = wave_sum(acc);
        if (lane == 0) qs[j] = acc + ipb[h * DHH + j];
    }
    __syncthreads();
    // r[h, e] for this quarter
    const int e = qa * 256 + t;
    const float* wk = ipw + (size_t)(DD + h * DHH) * DD;
    float acc = 0.f;
#pragma unroll 8
    for (int j = 0; j < DHH; ++j)
        acc += qs[j] * wk[(size_t)j * DD + e];
    (ws + WS_R)[h * DD + e] = acc * 0.125f;
    if (qa == 0 && t < 64) {
        float p = qs[t] * ipb[DD + h * DHH + t];
        p = wave_sum(p);
        if (t == 0) (ws + WS_C)[h] = p * 0.125f;
    }
}

// ---------------- fused MFMA, software-pipelined --------------
// block = (b, 128-row chunk), 4 waves; 8 tiles of 16 rows, LDS double-buffered.
// Per iter: scores(tt) | BAR | pack+write t(tt+1), issue loads t(tt+2) |
//           finish(tt) | PV(tt) | BAR.
// Staging map: srow = wv*4 + ((lane>>2)&3), e = (lane>>4)*16+(lane&3)*4 + 64j
//   -> write byte%128 = (lane&15)*8: conflict-free b64 writes.
// PV: mfma 16x16x32 with A zeroed for k>=16 lanes (g>=2); tr_reads issued in
//   two 16-read batches, one full lgkmcnt(0) drain each (2 drains/tile, was 4).
__global__ __launch_bounds__(256, 2)
void k_fused(const float* __restrict__ gr, const float* __restrict__ ws,
             float* __restrict__ attn_e, unsigned short* __restrict__ part,
             float* __restrict__ ssum) {
    extern __shared__ char smem[];
    const int b  = blockIdx.x >> 4;
    const int ck = blockIdx.x & 15;
    const int l0 = ck * CH;
    const int t  = threadIdx.x;
    const int wv = t >> 6, lane = t & 63;
    const int c16 = lane & 15, g = lane >> 4;
    const int estrip = wv * 256;            // this wave's e-strip

    // ---- prologue: pack r into B-frags (8 k-steps x 32 e), bias ----
    bf16x8 rpk[8];
#pragma unroll
    for (int ks = 0; ks < 8; ++ks) {
        const float* rp = ws + WS_R + (size_t)c16 * DD + estrip + ks * 32 + g * 8;
        u16x4 lo = pk4(*(const float4*)rp);
        u16x4 hi = pk4(*(const float4*)(rp + 4));
        bf16x8 r;
        r[0] = (short)lo[0]; r[1] = (short)lo[1]; r[2] = (short)lo[2]; r[3] = (short)lo[3];
        r[4] = (short)hi[0]; r[5] = (short)hi[1]; r[6] = (short)hi[2]; r[7] = (short)hi[3];
        rpk[ks] = r;
    }
    const float myc = (ws + WS_C)[c16];

    f32x4 pv[16];
#pragma unroll
    for (int i = 0; i < 16; ++i) pv[i] = (f32x4){0.f, 0.f, 0.f, 0.f};
    float s_acc = 0.f;

    // ---- staging geometry (conflict-free map) ----
    const int srow = wv * 4 + ((lane >> 2) & 3);   // row within 16-row tile
    const int scol = (lane >> 4) * 16 + (lane & 3) * 4;  // e base; e = scol+64j
    const float* gbase = gr + ((size_t)(b * LL + l0) + srow) * DD + scol;
    const int wr_base = (lane >> 4) * 512 + wv * 128 + ((lane >> 2) & 3) * 32 +
                        (lane & 3) * 8;

    float4 raw[16];
    // tile 0: load + pack + write buf0
#pragma unroll
    for (int j = 0; j < 16; ++j) raw[j] = *(const float4*)(gbase + 64 * j);
#pragma unroll
    for (int j = 0; j < 16; ++j)
        *(u16x4*)(smem + wr_base + j * 2048) = pk4(raw[j]);
    // issue tile 1 loads
#pragma unroll
    for (int j = 0; j < 16; ++j)
        raw[j] = *(const float4*)(gbase + 16 * DD + 64 * j);
    __syncthreads();

#pragma unroll 1
    for (int tt = 0; tt < NT; ++tt) {
        const char* rb = smem + (tt & 1) * 32768;
        // ---- scores(tt): 8 k-steps over this wave's e-strip ----
        f32x4 sa = {0.f, 0.f, 0.f, 0.f};
#pragma unroll
        for (int ks = 0; ks < 8; ++ks) {
            const int e16 = wv * 16 + ks * 2 + (g >> 1);
            const int byt = (e16 * 4 + (c16 >> 2)) * 128 + (c16 & 3) * 32 + (g & 1) * 16;
            bf16x8 a = *(const bf16x8*)(rb + byt);
            sa = MFMA(a, rpk[ks], sa);
        }
        *(f32x4*)(smem + RED_OFF + (wv * 64 + lane) * 16) = sa;
        __syncthreads();                    // red visible; buf[(tt+1)&1] free
        // ---- stage tile tt+1 (pack from in-flight regs), issue tt+2 ----
        if (tt < NT - 1) {
            char* wb = smem + ((tt + 1) & 1) * 32768;
#pragma unroll
            for (int j = 0; j < 16; ++j)
                *(u16x4*)(wb + wr_base + j * 2048) = pk4(raw[j]);
            if (tt < NT - 2) {
                const float* gs = gbase + (size_t)(tt + 2) * 16 * DD;
#pragma unroll
                for (int j = 0; j < 16; ++j)
                    raw[j] = *(const float4*)(gs + 64 * j);
            }
        }
        // ---- finish(tt): sum 4 wave-partials + bias, exp ----
        f32x4 tot = {myc, myc, myc, myc};
#pragma unroll
        for (int w2 = 0; w2 < 4; ++w2)
            tot += *(const f32x4*)(smem + RED_OFF + (w2 * 64 + lane) * 16);
        f32x4 ex;                           // no max-shift: |score| ~ O(1)
        ex[0] = __expf(tot[0]); ex[1] = __expf(tot[1]);
        ex[2] = __expf(tot[2]); ex[3] = __expf(tot[3]);
        u16x4 wp = pk4(make_float4(ex[0], ex[1], ex[2], ex[3]));
        *(u16x4*)(smem + WT_OFF + wv * 512 + c16 * 32 + g * 8) = wp;
        if (wv == 0) {                      // attn (unnormalized exp) store
            float* ap = attn_e + ((size_t)b * HH + c16) * LL + l0 + tt * 16 + g * 4;
            *(float4*)ap = make_float4(ex[0], ex[1], ex[2], ex[3]);
        }
        s_acc += ex[0] + ex[1] + ex[2] + ex[3];
        // ---- PV(tt): A = wt (zero for k>=16 lanes), B = tr-reads of G ----
        bf16x8 afrag;
        if (g < 2) {
            afrag = *(const bf16x8*)(smem + WT_OFF + wv * 512 + c16 * 32 + g * 16);
        } else {
            afrag = (bf16x8){0, 0, 0, 0, 0, 0, 0, 0};
        }
#pragma unroll
        for (int pp2 = 0; pp2 < 2; ++pp2) { // two 16-read batches
            u32x2 q[16];
#pragma unroll
            for (int n2 = 0; n2 < 8; ++n2) {
                const int est = wv * 16 + pp2 * 8 + n2;
                const unsigned ta = (unsigned)((tt & 1) * 32768 + est * 512 +
                                               (g & 1) * 256 + c16 * 8);
                asm volatile("ds_read_b64_tr_b16 %0, %1"
                             : "=v"(q[n2 * 2]) : "v"(ta));
                asm volatile("ds_read_b64_tr_b16 %0, %1 offset:128"
                             : "=v"(q[n2 * 2 + 1]) : "v"(ta));
            }
            asm volatile("s_waitcnt lgkmcnt(0)" ::: "memory");
            __builtin_amdgcn_sched_barrier(0);
#pragma unroll
            for (int n2 = 0; n2 < 8; ++n2) {
                union { unsigned u[4]; bf16x8 v; } bb;
                bb.u[0] = q[n2 * 2][0];     bb.u[1] = q[n2 * 2][1];
                bb.u[2] = q[n2 * 2 + 1][0]; bb.u[3] = q[n2 * 2 + 1][1];
                pv[pp2 * 8 + n2] = MFMA(afrag, bb.v, pv[pp2 * 8 + n2]);
            }
        }
        __syncthreads();                    // stage(tt+1) visible; red free
    }
    // ---- epilogue: ssum + partials (bf16) ----
    float sv = s_acc;
    sv += __shfl_xor(sv, 16, 64);
    sv += __shfl_xor(sv, 32, 64);
    if (wv == 0 && lane < 16)
        ssum[((size_t)b * NCK + ck) * HH + c16] = sv;
    unsigned short* pp = part + ((size_t)b * NCK + ck) * (HH * DD);
#pragma unroll
    for (int nt = 0; nt < 16; ++nt) {
#pragma unroll
        for (int r2 = 0; r2 < 4; ++r2) {
            ushort2 u = pk2(pv[nt][r2], pv[nt][r2]);
            pp[(size_t)(g * 4 + r2) * DD + estrip + nt * 16 + c16] = u.x;
        }
    }
}

// ---------------- combine + attn-normalize + Wv: ctx[b, h*64+j] ------------
__global__ void k_ctx(const float* __restrict__ ipw, const float* __restrict__ ipb,
                      const unsigned short* __restrict__ part,
                      const float* __restrict__ ssum,
                      float* __restrict__ attn_e, float* __restrict__ ctx) {
    const int bh = blockIdx.x, b = bh >> 4, h = bh & 15;   // 512 blocks
    const int t = threadIdx.x, w = t >> 6, lane = t & 63;  // 256
    float S = 0.f;
#pragma unroll
    for (int c = 0; c < NCK; ++c) S += ssum[((size_t)b * NCK + c) * HH + h];
    const float inv = 1.0f / S;
    float4* ar = (float4*)(attn_e + (size_t)bh * LL);
#pragma unroll
    for (int i = 0; i < 2; ++i) {
        float4 v = ar[t + 256 * i];
        v.x *= inv; v.y *= inv; v.z *= inv; v.w *= inv;
        ar[t + 256 * i] = v;
    }
    __shared__ float Xl[DD];
    float4 x = {0.f, 0.f, 0.f, 0.f};
#pragma unroll
    for (int c = 0; c < NCK; ++c) {
        u16x4 p = *(const u16x4*)(part + ((size_t)b * NCK + c) * (HH * DD) +
                                  (size_t)h * DD + t * 4);
        x.x += bf2f(p[0]); x.y += bf2f(p[1]);
        x.z += bf2f(p[2]); x.w += bf2f(p[3]);
    }
    float4 xs = {x.x * inv, x.y * inv, x.z * inv, x.w * inv};
    ((float4*)Xl)[t] = xs;
    __syncthreads();
    for (int jj = 0; jj < 16; ++jj) {
        const int j = w * 16 + jj;
        const float* row = ipw + (size_t)(2 * DD + h * DHH + j) * DD;
        float acc = 0.f;
#pragma unroll
        for (int it = 0; it < 4; ++it) {
            float4 a = ((const float4*)row)[lane + 64 * it];
            float4 p = ((const float4*)Xl)[lane + 64 * it];
            acc += a.x * p.x + a.y * p.y + a.z * p.z + a.w * p.w;
        }
        acc = wave_sum(acc);
        if (lane == 0) ctx[(size_t)b * DD + h * DHH + j] = acc + ipb[2 * DD + h * DHH + j];
    }
}

// ---------------- y[b, d'] = out_w[d',:]·ctx[b,:] + out_b ----------------
__global__ void k_y(const float* __restrict__ ow, const float* __restrict__ ob,
                    const float* __restrict__ ctx, float* __restrict__ y) {
    const int blk = blockIdx.x, b = blk >> 4, ch = blk & 15;  // 512 blocks
    const int t = threadIdx.x, w = t >> 6, lane = t & 63;     // 256
    __shared__ float Xl[DD];
    ((float4*)Xl)[t] = ((const float4*)(ctx + (size_t)b * DD))[t];
    __syncthreads();
    for (int jj = 0; jj < 16; ++jj) {
        const int d = ch * 64 + w * 16 + jj;
        const float* row = ow + (size_t)d * DD;
        float acc = 0.f;
#pragma unroll
        for (int it = 0; it < 4; ++it) {
            float4 a = ((const float4*)row)[lane + 64 * it];
            float4 p = ((const float4*)Xl)[lane + 64 * it];
            acc += a.x * p.x + a.y * p.y + a.z * p.z + a.w * p.w;
        }
        acc = wave_sum(acc);
        if (lane == 0) y[(size_t)b * DD + d] = acc + ob[d];
    }
}

// ---------------- final LN -> pooled output ----------------
__global__ void k_lnout(const float* __restrict__ y, const float* __restrict__ on_w,
                        const float* __restrict__ on_b, float* __restrict__ outp) {
    const int b = blockIdx.x, t = threadIdx.x;   // 32 blocks, 256 threads
    const float4 x = ((const float4*)(y + (size_t)b * DD))[t];
    float s  = x.x + x.y + x.z + x.w;
    float s2 = x.x * x.x + x.y * x.y + x.z * x.z + x.w * x.w;
    __shared__ float rs[4], rs2[4];
    s = wave_sum(s); s2 = wave_sum(s2);
    const int w = t >> 6, lane = t & 63;
    if (lane == 0) { rs[w] = s; rs2[w] = s2; }
    __syncthreads();
    s  = rs[0] + rs[1] + rs[2] + rs[3];
    s2 = rs2[0] + rs2[1] + rs2[2] + rs2[3];
    const float mu  = s * (1.0f / DD);
    const float var = s2 * (1.0f / DD) - mu * mu;
    const float rstd = rsqrtf(var + 1e-5f);
    const float4 w4 = ((const float4*)on_w)[t];
    const float4 b4 = ((const float4*)on_b)[t];
    float4 o;
    o.x = (x.x - mu) * rstd * w4.x + b4.x;
    o.y = (x.y - mu) * rstd * w4.y + b4.y;
    o.z = (x.z - mu) * rstd * w4.z + b4.z;
    o.w = (x.w - mu) * rstd * w4.w + b4.w;
    ((float4*)(outp + (size_t)b * DD))[t] = o;
}

extern "C" void kernel_launch(void* const* d_in, const int* in_sizes, int n_in,
                              void* d_out, int out_size, void* d_ws, size_t ws_size,
                              hipStream_t stream) {
    const float* gr   = (const float*)d_in[0];
    const float* sq   = (const float*)d_in[1];
    const float* qn_w = (const float*)d_in[2];
    const float* qn_b = (const float*)d_in[3];
    const float* ipw  = (const float*)d_in[4];
    const float* ipb  = (const float*)d_in[5];
    const float* ow   = (const float*)d_in[6];
    const float* ob   = (const float*)d_in[7];
    const float* on_w = (const float*)d_in[8];
    const float* on_b = (const float*)d_in[9];
    const int*   pos  = (const int*)d_in[10];

    float* out  = (float*)d_out;
    float* attn = out + BB * DD;           // output 1; holds exp(score) until k_ctx norms
    float* ws   = (float*)d_ws;
    unsigned short* part16 = (unsigned short*)(ws + WS_PART);

    hipFuncSetAttribute((const void*)k_fused,
                        hipFuncAttributeMaxDynamicSharedMemorySize, SMEM_BYTES);

    k_qr<<<64, 256, 0, stream>>>(sq, qn_w, qn_b, pos, ipw, ipb, ws);
    k_fused<<<BB * NCK, 256, SMEM_BYTES, stream>>>(gr, ws, attn,
                                                   part16, ws + WS_SSUM);
    k_ctx<<<BB * HH, 256, 0, stream>>>(ipw, ipb, part16, ws + WS_SSUM,
                                       attn, ws + WS_CTX);
    k_y<<<BB * 16, 256, 0, stream>>>(ow, ob, ws + WS_CTX, ws + WS_Y);
    k_lnout<<<BB, 256, 0, stream>>>(ws + WS_Y, on_w, on_b, out);
}

// Round 12
// 103.848 us; speedup vs baseline: 1.0432x; 1.0432x over previous
//
#include <hip/hip_runtime.h>
#include <math.h>

#define BB 32
#define LL 2048
#define DD 1024
#define HH 16
#define DHH 64
#define NCK 16         // chunks per batch
#define CH  128        // rows per chunk
#define NT  8          // 16-row tiles per chunk

// ---- ws layout (float offsets) ----
#define WS_Q     1024       // 1024
#define WS_R     2048       // 16*1024
#define WS_C     18432      // 64 (16 used)
#define WS_CTX   19008      // 32768
#define WS_Y     51776      // 32768
#define WS_SSUM  84544      // 32*16*16 = 8192
#define WS_PART  92736      // 32*16*16*1024 bf16 = 16 MB

// ---- k_fused dynamic LDS layout (bytes) ----
// G tile buffers: 2 x (16 rows x 1024 e bf16, [4 l][16 e]-subtiled) = 2x32768
//   byte(l,e) = (e>>4)*512 + (l>>2)*128 + (l&3)*32 + (e&15)*2
#define RED_OFF  65536      // 8 waves x 64 lanes x 4 f32 = 8192
#define WT_OFF   73728      // 8 waves x 16 h x 16 l bf16 = 4096
#define SMEM_BYTES 77824

typedef __attribute__((ext_vector_type(8))) short    bf16x8;
typedef __attribute__((ext_vector_type(4))) float    f32x4;
typedef __attribute__((ext_vector_type(2))) unsigned u32x2;
typedef __attribute__((ext_vector_type(4))) unsigned short u16x4;

#define MFMA(a, b, c) __builtin_amdgcn_mfma_f32_16x16x32_bf16(a, b, c, 0, 0, 0)

__device__ __forceinline__ unsigned short f2bf(float f) {   // RNE f32->bf16
    unsigned u = __float_as_uint(f);
    return (unsigned short)((u + 0x7FFFu + ((u >> 16) & 1u)) >> 16);
}
__device__ __forceinline__ u16x4 pk4(float4 f) {
    u16x4 r; r[0] = f2bf(f.x); r[1] = f2bf(f.y); r[2] = f2bf(f.z); r[3] = f2bf(f.w);
    return r;
}
__device__ __forceinline__ float bf2f(unsigned short u) {
    return __uint_as_float((unsigned)u << 16);
}
__device__ __forceinline__ float wave_sum(float v) {
#pragma unroll
    for (int s = 32; s >= 1; s >>= 1) v += __shfl_xor(v, s, 64);
    return v;
}

// ---------------- K1: q = Wq @ LN(sq[pos]) + bq  (LN fused, wave/output) ----
__global__ void k_q(const float* __restrict__ sq, const float* __restrict__ qn_w,
                    const float* __restrict__ qn_b, const int* __restrict__ pos,
                    const float* __restrict__ ipw, const float* __restrict__ ipb,
                    float* __restrict__ ws) {
    const int t = threadIdx.x;              // 256 threads
    const int w = t >> 6, lane = t & 63;
    __shared__ float q0s[DD];
    __shared__ float rs[4], rs2[4];
    {   // redundant per-block LN of the single query row (4 KB, L2-hot)
        const float4 x = ((const float4*)(sq + (size_t)pos[0] * DD))[t];
        float s  = x.x + x.y + x.z + x.w;
        float s2 = x.x * x.x + x.y * x.y + x.z * x.z + x.w * x.w;
        s = wave_sum(s); s2 = wave_sum(s2);
        if (lane == 0) { rs[w] = s; rs2[w] = s2; }
        __syncthreads();
        s  = rs[0] + rs[1] + rs[2] + rs[3];
        s2 = rs2[0] + rs2[1] + rs2[2] + rs2[3];
        const float mu  = s * (1.0f / DD);
        const float var = s2 * (1.0f / DD) - mu * mu;
        const float rstd = rsqrtf(var + 1e-5f);
        const float4 w4 = ((const float4*)qn_w)[t];
        const float4 b4 = ((const float4*)qn_b)[t];
        float4 o;
        o.x = (x.x - mu) * rstd * w4.x + b4.x;
        o.y = (x.y - mu) * rstd * w4.y + b4.y;
        o.z = (x.z - mu) * rstd * w4.z + b4.z;
        o.w = (x.w - mu) * rstd * w4.w + b4.w;
        ((float4*)q0s)[t] = o;
    }
    __syncthreads();
    const int d = blockIdx.x * 4 + w;       // 256 blocks * 4 waves = 1024 outputs
    const float* row = ipw + (size_t)d * DD;
    float acc = 0.f;
#pragma unroll
    for (int it = 0; it < 4; ++it) {
        float4 a = ((const float4*)row)[lane + 64 * it];
        float4 b = ((const float4*)q0s)[lane + 64 * it];
        acc += a.x * b.x + a.y * b.y + a.z * b.z + a.w * b.w;
    }
    acc = wave_sum(acc);
    if (lane == 0) (ws + WS_Q)[d] = acc + ipb[d];
}

// ---------------- K2: r_s[h,e] = scale * sum_j q[h,j] Wk[h*64+j, e] --------
__global__ void k_r(const float* __restrict__ ipw, const float* __restrict__ ipb,
                    float* __restrict__ ws) {
    const int h = blockIdx.x >> 2, qa = blockIdx.x & 3;
    const int t = threadIdx.x;
    const int e = qa * 256 + t;
    const float* q = ws + WS_Q;
    const float* wk = ipw + (size_t)(DD + h * DHH) * DD;
    float acc = 0.f;
#pragma unroll 8
    for (int j = 0; j < DHH; ++j)
        acc += q[h * DHH + j] * wk[(size_t)j * DD + e];
    (ws + WS_R)[h * DD + e] = acc * 0.125f;
    if (qa == 0 && t < 64) {
        float p = q[h * DHH + t] * ipb[DD + h * DHH + t];
        p = wave_sum(p);
        if (t == 0) (ws + WS_C)[h] = p * 0.125f;
    }
}

// ---------------- fused MFMA, software-pipelined, 8 waves --------------
// block = (b, 128-row chunk), 8 waves (512 thr); 8 tiles of 16 rows, LDS dbuf.
// Per iter: scores(tt) | BAR | pack+write t(tt+1), issue loads t(tt+2) |
//           finish(tt) | PV(tt) | BAR.
// Per-wave arrays halved vs R10 (raw 8, pv 8, rpk 4, q 8) targeting VGPR<=128
// so 2 x 512-thr blocks co-reside per CU (LDS 2x76KB <= 160KB) -> 4 waves/SIMD.
// __launch_bounds__(512,2) = NON-forcing (R3 lesson: never hard-clamp VGPR).
// Staging map: row = ((lane>>2)&3) + (wv&3)*4,
//              e   = (lane&3)*4 + ((lane>>4) + (wv>>2)*4)*16 + 128j
//   -> write byte%128 = 8*(lane&15): conflict-free b64 writes per 16-lane grp.
__global__ __launch_bounds__(512, 2)
void k_fused(const float* __restrict__ gr, const float* __restrict__ ws,
             float* __restrict__ attn_e, unsigned short* __restrict__ part,
             float* __restrict__ ssum) {
    extern __shared__ char smem[];
    const int b  = blockIdx.x >> 4;
    const int ck = blockIdx.x & 15;
    const int l0 = ck * CH;
    const int t  = threadIdx.x;
    const int wv = t >> 6, lane = t & 63;
    const int c16 = lane & 15, g = lane >> 4;
    const int estrip = wv * 128;            // this wave's e-strip

    // ---- prologue: pack r into B-frags (4 k-steps x 32 e), bias ----
    bf16x8 rpk[4];
#pragma unroll
    for (int ks = 0; ks < 4; ++ks) {
        const float* rp = ws + WS_R + (size_t)c16 * DD + estrip + ks * 32 + g * 8;
        float4 f0 = *(const float4*)rp, f1 = *(const float4*)(rp + 4);
        bf16x8 r;
        r[0] = (short)f2bf(f0.x); r[1] = (short)f2bf(f0.y);
        r[2] = (short)f2bf(f0.z); r[3] = (short)f2bf(f0.w);
        r[4] = (short)f2bf(f1.x); r[5] = (short)f2bf(f1.y);
        r[6] = (short)f2bf(f1.z); r[7] = (short)f2bf(f1.w);
        rpk[ks] = r;
    }
    const float myc = (ws + WS_C)[c16];

    f32x4 pv[8];
#pragma unroll
    for (int i = 0; i < 8; ++i) pv[i] = (f32x4){0.f, 0.f, 0.f, 0.f};
    float s_acc = 0.f;

    // ---- staging geometry (conflict-free, 512 threads) ----
    const int srow = ((lane >> 2) & 3) + (wv & 3) * 4;   // row 0..15
    const int se0  = (lane & 3) * 4 + ((lane >> 4) + (wv >> 2) * 4) * 16;
    const float* gbase = gr + ((size_t)(b * LL + l0) + srow) * DD + se0;
    const int wr_base = ((lane >> 4) + (wv >> 2) * 4) * 512 + (wv & 3) * 128 +
                        ((lane >> 2) & 3) * 32 + (lane & 3) * 8;

    float4 raw[8];
    // tile 0: load + pack + write buf0
#pragma unroll
    for (int j = 0; j < 8; ++j) raw[j] = *(const float4*)(gbase + 128 * j);
#pragma unroll
    for (int j = 0; j < 8; ++j)
        *(u16x4*)(smem + wr_base + j * 4096) = pk4(raw[j]);
    // issue tile 1 loads
#pragma unroll
    for (int j = 0; j < 8; ++j)
        raw[j] = *(const float4*)(gbase + 16 * DD + 128 * j);
    __syncthreads();

#pragma unroll 1
    for (int tt = 0; tt < NT; ++tt) {
        const char* rb = smem + (tt & 1) * 32768;
        // ---- scores(tt): 4 k-steps over this wave's 128-e strip ----
        f32x4 sa = {0.f, 0.f, 0.f, 0.f};
#pragma unroll
        for (int ks = 0; ks < 4; ++ks) {
            const int e16 = wv * 8 + ks * 2 + (g >> 1);
            const int byt = (e16 * 4 + (c16 >> 2)) * 128 + (c16 & 3) * 32 + (g & 1) * 16;
            bf16x8 a = *(const bf16x8*)(rb + byt);
            sa = MFMA(a, rpk[ks], sa);
        }
        *(f32x4*)(smem + RED_OFF + (wv * 64 + lane) * 16) = sa;
        __syncthreads();                    // red visible; buf[(tt+1)&1] free
        // ---- stage tile tt+1 (pack from in-flight regs), issue tt+2 ----
        if (tt < NT - 1) {
            char* wb = smem + ((tt + 1) & 1) * 32768;
#pragma unroll
            for (int j = 0; j < 8; ++j)
                *(u16x4*)(wb + wr_base + j * 4096) = pk4(raw[j]);
            if (tt < NT - 2) {
                const float* gs = gbase + (size_t)(tt + 2) * 16 * DD;
#pragma unroll
                for (int j = 0; j < 8; ++j)
                    raw[j] = *(const float4*)(gs + 128 * j);
            }
        }
        // ---- finish(tt): sum 8 wave-partials + bias, exp ----
        f32x4 tot = {myc, myc, myc, myc};
#pragma unroll
        for (int w2 = 0; w2 < 8; ++w2)
            tot += *(const f32x4*)(smem + RED_OFF + (w2 * 64 + lane) * 16);
        f32x4 ex;                           // no max-shift: |score| ~ O(1)
        ex[0] = __expf(tot[0]); ex[1] = __expf(tot[1]);
        ex[2] = __expf(tot[2]); ex[3] = __expf(tot[3]);
        *(u16x4*)(smem + WT_OFF + wv * 512 + c16 * 32 + g * 8) =
            pk4(make_float4(ex[0], ex[1], ex[2], ex[3]));
        if (wv == (tt & 7)) {               // attn store, rotated across waves
            float* ap = attn_e + ((size_t)b * HH + c16) * LL + l0 + tt * 16 + g * 4;
            *(float4*)ap = make_float4(ex[0], ex[1], ex[2], ex[3]);
        }
        s_acc += ex[0] + ex[1] + ex[2] + ex[3];
        // ---- PV(tt): A = wt (zero for k>=16 lanes), B = tr-reads of G ----
        bf16x8 afrag;
        if (g < 2) {
            afrag = *(const bf16x8*)(smem + WT_OFF + wv * 512 + c16 * 32 + g * 16);
        } else {
            afrag = (bf16x8){0, 0, 0, 0, 0, 0, 0, 0};
        }
#pragma unroll
        for (int grp = 0; grp < 2; ++grp) {
            u32x2 q[8];
#pragma unroll
            for (int n2 = 0; n2 < 4; ++n2) {
                const int est = wv * 8 + grp * 4 + n2;
                const unsigned ta = (unsigned)((tt & 1) * 32768 + est * 512 +
                                               (g & 1) * 256 + c16 * 8);
                asm volatile("ds_read_b64_tr_b16 %0, %1"
                             : "=v"(q[n2 * 2]) : "v"(ta));
                asm volatile("ds_read_b64_tr_b16 %0, %1 offset:128"
                             : "=v"(q[n2 * 2 + 1]) : "v"(ta));
            }
            asm volatile("s_waitcnt lgkmcnt(0)" ::: "memory");
            __builtin_amdgcn_sched_barrier(0);
#pragma unroll
            for (int n2 = 0; n2 < 4; ++n2) {
                union { unsigned u[4]; bf16x8 v; } bb;
                bb.u[0] = q[n2 * 2][0];     bb.u[1] = q[n2 * 2][1];
                bb.u[2] = q[n2 * 2 + 1][0]; bb.u[3] = q[n2 * 2 + 1][1];
                pv[grp * 4 + n2] = MFMA(afrag, bb.v, pv[grp * 4 + n2]);
            }
        }
        __syncthreads();                    // stage(tt+1) visible; red free
    }
    // ---- epilogue: ssum + partials (bf16) ----
    float sv = s_acc;                       // identical in all waves
    sv += __shfl_xor(sv, 16, 64);
    sv += __shfl_xor(sv, 32, 64);
    if (wv == 0 && lane < 16)
        ssum[((size_t)b * NCK + ck) * HH + c16] = sv;
    unsigned short* pp = part + ((size_t)b * NCK + ck) * (HH * DD);
#pragma unroll
    for (int nt = 0; nt < 8; ++nt) {
#pragma unroll
        for (int r2 = 0; r2 < 4; ++r2)
            pp[(size_t)(g * 4 + r2) * DD + estrip + nt * 16 + c16] = f2bf(pv[nt][r2]);
    }
}

// ---------------- combine + attn-normalize + Wv: ctx[b, h*64+j] ------------
__global__ void k_ctx(const float* __restrict__ ipw, const float* __restrict__ ipb,
                      const unsigned short* __restrict__ part,
                      const float* __restrict__ ssum,
                      float* __restrict__ attn_e, float* __restrict__ ctx) {
    const int bh = blockIdx.x, b = bh >> 4, h = bh & 15;   // 512 blocks
    const int t = threadIdx.x, w = t >> 6, lane = t & 63;  // 256
    float S = 0.f;
#pragma unroll
    for (int c = 0; c < NCK; ++c) S += ssum[((size_t)b * NCK + c) * HH + h];
    const float inv = 1.0f / S;
    float4* ar = (float4*)(attn_e + (size_t)bh * LL);
#pragma unroll
    for (int i = 0; i < 2; ++i) {
        float4 v = ar[t + 256 * i];
        v.x *= inv; v.y *= inv; v.z *= inv; v.w *= inv;
        ar[t + 256 * i] = v;
    }
    __shared__ float Xl[DD];
    float4 x = {0.f, 0.f, 0.f, 0.f};
#pragma unroll
    for (int c = 0; c < NCK; ++c) {
        u16x4 p = *(const u16x4*)(part + ((size_t)b * NCK + c) * (HH * DD) +
                                  (size_t)h * DD + t * 4);
        x.x += bf2f(p[0]); x.y += bf2f(p[1]);
        x.z += bf2f(p[2]); x.w += bf2f(p[3]);
    }
    float4 xs = {x.x * inv, x.y * inv, x.z * inv, x.w * inv};
    ((float4*)Xl)[t] = xs;
    __syncthreads();
    for (int jj = 0; jj < 16; ++jj) {
        const int j = w * 16 + jj;
        const float* row = ipw + (size_t)(2 * DD + h * DHH + j) * DD;
        float acc = 0.f;
#pragma unroll
        for (int it = 0; it < 4; ++it) {
            float4 a = ((const float4*)row)[lane + 64 * it];
            float4 p = ((const float4*)Xl)[lane + 64 * it];
            acc += a.x * p.x + a.y * p.y + a.z * p.z + a.w * p.w;
        }
        acc = wave_sum(acc);
        if (lane == 0) ctx[(size_t)b * DD + h * DHH + j] = acc + ipb[2 * DD + h * DHH + j];
    }
}

// ---------------- y[b, d'] = out_w[d',:]·ctx[b,:] + out_b ----------------
__global__ void k_y(const float* __restrict__ ow, const float* __restrict__ ob,
                    const float* __restrict__ ctx, float* __restrict__ y) {
    const int blk = blockIdx.x, b = blk >> 4, ch = blk & 15;  // 512 blocks
    const int t = threadIdx.x, w = t >> 6, lane = t & 63;     // 256
    __shared__ float Xl[DD];
    ((float4*)Xl)[t] = ((const float4*)(ctx + (size_t)b * DD))[t];
    __syncthreads();
    for (int jj = 0; jj < 16; ++jj) {
        const int d = ch * 64 + w * 16 + jj;
        const float* row = ow + (size_t)d * DD;
        float acc = 0.f;
#pragma unroll
        for (int it = 0; it < 4; ++it) {
            float4 a = ((const float4*)row)[lane + 64 * it];
            float4 p = ((const float4*)Xl)[lane + 64 * it];
            acc += a.x * p.x + a.y * p.y + a.z * p.z + a.w * p.w;
        }
        acc = wave_sum(acc);
        if (lane == 0) y[(size_t)b * DD + d] = acc + ob[d];
    }
}

// ---------------- final LN -> pooled output ----------------
__global__ void k_lnout(const float* __restrict__ y, const float* __restrict__ on_w,
                        const float* __restrict__ on_b, float* __restrict__ outp) {
    const int b = blockIdx.x, t = threadIdx.x;   // 32 blocks, 256 threads
    const float4 x = ((const float4*)(y + (size_t)b * DD))[t];
    float s  = x.x + x.y + x.z + x.w;
    float s2 = x.x * x.x + x.y * x.y + x.z * x.z + x.w * x.w;
    __shared__ float rs[4], rs2[4];
    s = wave_sum(s); s2 = wave_sum(s2);
    const int w = t >> 6, lane = t & 63;
    if (lane == 0) { rs[w] = s; rs2[w] = s2; }
    __syncthreads();
    s  = rs[0] + rs[1] + rs[2] + rs[3];
    s2 = rs2[0] + rs2[1] + rs2[2] + rs2[3];
    const float mu  = s * (1.0f / DD);
    const float var = s2 * (1.0f / DD) - mu * mu;
    const float rstd = rsqrtf(var + 1e-5f);
    const float4 w4 = ((const float4*)on_w)[t];
    const float4 b4 = ((const float4*)on_b)[t];
    float4 o;
    o.x = (x.x - mu) * rstd * w4.x + b4.x;
    o.y = (x.y - mu) * rstd * w4.y + b4.y;
    o.z = (x.z - mu) * rstd * w4.z + b4.z;
    o.w = (x.w - mu) * rstd * w4.w + b4.w;
    ((float4*)(outp + (size_t)b * DD))[t] = o;
}

extern "C" void kernel_launch(void* const* d_in, const int* in_sizes, int n_in,
                              void* d_out, int out_size, void* d_ws, size_t ws_size,
                              hipStream_t stream) {
    const float* gr   = (const float*)d_in[0];
    const float* sq   = (const float*)d_in[1];
    const float* qn_w = (const float*)d_in[2];
    const float* qn_b = (const float*)d_in[3];
    const float* ipw  = (const float*)d_in[4];
    const float* ipb  = (const float*)d_in[5];
    const float* ow   = (const float*)d_in[6];
    const float* ob   = (const float*)d_in[7];
    const float* on_w = (const float*)d_in[8];
    const float* on_b = (const float*)d_in[9];
    const int*   pos  = (const int*)d_in[10];

    float* out  = (float*)d_out;
    float* attn = out + BB * DD;           // output 1; holds exp(score) until k_ctx norms
    float* ws   = (float*)d_ws;
    unsigned short* part16 = (unsigned short*)(ws + WS_PART);

    hipFuncSetAttribute((const void*)k_fused,
                        hipFuncAttributeMaxDynamicSharedMemorySize, SMEM_BYTES);

    k_q<<<256, 256, 0, stream>>>(sq, qn_w, qn_b, pos, ipw, ipb, ws);
    k_r<<<64, 256, 0, stream>>>(ipw, ipb, ws);
    k_fused<<<BB * NCK, 512, SMEM_BYTES, stream>>>(gr, ws, attn,
                                                   part16, ws + WS_SSUM);
    k_ctx<<<BB * HH, 256, 0, stream>>>(ipw, ipb, part16, ws + WS_SSUM,
                                       attn, ws + WS_CTX);
    k_y<<<BB * 16, 256, 0, stream>>>(ow, ob, ws + WS_CTX, ws + WS_Y);
    k_lnout<<<BB, 256, 0, stream>>>(ws + WS_Y, on_w, on_b, out);
}

// Round 13
// 101.099 us; speedup vs baseline: 1.0715x; 1.0272x over previous
//
#include <hip/hip_runtime.h>
#include <hip/hip_bf16.h>
#include <math.h>

#define BB 32
#define LL 2048
#define DD 1024
#define HH 16
#define DHH 64
#define NCK 16         // chunks per batch
#define CH  128        // rows per chunk
#define NT  8          // 16-row tiles per chunk

// ---- ws layout (float offsets) ----
#define WS_Q     1024       // 1024
#define WS_R     2048       // 16*1024
#define WS_C     18432      // 64 (16 used)
#define WS_CTX   19008      // 32768
#define WS_Y     51776      // 32768
#define WS_SSUM  84544      // 32*16*16 = 8192
#define WS_PART  92736      // 32*16*16*1024 bf16 = 16 MB

// ---- k_fused dynamic LDS layout (bytes) ----
// G tile buffers: 2 x (16 rows x 1024 e bf16, [4 l][16 e]-subtiled) = 2x32768
//   byte(l,e) = (e>>4)*512 + (l>>2)*128 + (l&3)*32 + (e&15)*2
#define RED_OFF  65536      // 8 waves x 64 lanes x 4 f32 = 8192
#define WT_OFF   73728      // 8 waves x 16 h x 16 l bf16 = 4096
#define SMEM_BYTES 77824

typedef __attribute__((ext_vector_type(8))) short    bf16x8;
typedef __attribute__((ext_vector_type(4))) float    f32x4;
typedef __attribute__((ext_vector_type(2))) unsigned u32x2;
typedef __attribute__((ext_vector_type(4))) unsigned short u16x4;

#define MFMA(a, b, c) __builtin_amdgcn_mfma_f32_16x16x32_bf16(a, b, c, 0, 0, 0)

__device__ __forceinline__ unsigned short f2bf(float f) {   // RNE f32->bf16
    unsigned u = __float_as_uint(f);
    return (unsigned short)((u + 0x7FFFu + ((u >> 16) & 1u)) >> 16);
}
// hot-path pack: v_cvt_pk_bf16_f32 via builtin (same RNE as f2bf)
__device__ __forceinline__ u16x4 pk4(float4 f) {
    __hip_bfloat162 a = __float22bfloat162_rn(make_float2(f.x, f.y));
    __hip_bfloat162 b = __float22bfloat162_rn(make_float2(f.z, f.w));
    ushort2 ua = *reinterpret_cast<ushort2*>(&a);
    ushort2 ub = *reinterpret_cast<ushort2*>(&b);
    u16x4 r; r[0] = ua.x; r[1] = ua.y; r[2] = ub.x; r[3] = ub.y;
    return r;
}
__device__ __forceinline__ float bf2f(unsigned short u) {
    return __uint_as_float((unsigned)u << 16);
}
__device__ __forceinline__ float wave_sum(float v) {
#pragma unroll
    for (int s = 32; s >= 1; s >>= 1) v += __shfl_xor(v, s, 64);
    return v;
}

// ---------------- K1: q = Wq @ LN(sq[pos]) + bq  (LN fused, wave/output) ----
__global__ void k_q(const float* __restrict__ sq, const float* __restrict__ qn_w,
                    const float* __restrict__ qn_b, const int* __restrict__ pos,
                    const float* __restrict__ ipw, const float* __restrict__ ipb,
                    float* __restrict__ ws) {
    const int t = threadIdx.x;              // 256 threads
    const int w = t >> 6, lane = t & 63;
    __shared__ float q0s[DD];
    __shared__ float rs[4], rs2[4];
    {   // redundant per-block LN of the single query row (4 KB, L2-hot)
        const float4 x = ((const float4*)(sq + (size_t)pos[0] * DD))[t];
        float s  = x.x + x.y + x.z + x.w;
        float s2 = x.x * x.x + x.y * x.y + x.z * x.z + x.w * x.w;
        s = wave_sum(s); s2 = wave_sum(s2);
        if (lane == 0) { rs[w] = s; rs2[w] = s2; }
        __syncthreads();
        s  = rs[0] + rs[1] + rs[2] + rs[3];
        s2 = rs2[0] + rs2[1] + rs2[2] + rs2[3];
        const float mu  = s * (1.0f / DD);
        const float var = s2 * (1.0f / DD) - mu * mu;
        const float rstd = rsqrtf(var + 1e-5f);
        const float4 w4 = ((const float4*)qn_w)[t];
        const float4 b4 = ((const float4*)qn_b)[t];
        float4 o;
        o.x = (x.x - mu) * rstd * w4.x + b4.x;
        o.y = (x.y - mu) * rstd * w4.y + b4.y;
        o.z = (x.z - mu) * rstd * w4.z + b4.z;
        o.w = (x.w - mu) * rstd * w4.w + b4.w;
        ((float4*)q0s)[t] = o;
    }
    __syncthreads();
    const int d = blockIdx.x * 4 + w;       // 256 blocks * 4 waves = 1024 outputs
    const float* row = ipw + (size_t)d * DD;
    float acc = 0.f;
#pragma unroll
    for (int it = 0; it < 4; ++it) {
        float4 a = ((const float4*)row)[lane + 64 * it];
        float4 b = ((const float4*)q0s)[lane + 64 * it];
        acc += a.x * b.x + a.y * b.y + a.z * b.z + a.w * b.w;
    }
    acc = wave_sum(acc);
    if (lane == 0) (ws + WS_Q)[d] = acc + ipb[d];
}

// ------- K2: r_s[h,e] = scale * sum_j q[h,j] Wk[h*64+j, e]  (256 blocks) ----
// block = (h, 64-e slice), 64 threads (1 wave): 4x the parallelism of R12.
__global__ void k_r(const float* __restrict__ ipw, const float* __restrict__ ipb,
                    float* __restrict__ ws) {
    const int h = blockIdx.x >> 4, s = blockIdx.x & 15;
    const int t = threadIdx.x;              // 64 threads
    const int e = s * 64 + t;
    const float* q = ws + WS_Q;
    const float* wk = ipw + (size_t)(DD + h * DHH) * DD;
    float acc = 0.f;
#pragma unroll 8
    for (int j = 0; j < DHH; ++j)
        acc += q[h * DHH + j] * wk[(size_t)j * DD + e];
    (ws + WS_R)[h * DD + e] = acc * 0.125f;
    if (s == 0) {
        float p = q[h * DHH + t] * ipb[DD + h * DHH + t];
        p = wave_sum(p);
        if (t == 0) (ws + WS_C)[h] = p * 0.125f;
    }
}

// ---------------- fused MFMA, software-pipelined, 8 waves --------------
// block = (b, 128-row chunk), 8 waves (512 thr); 8 tiles of 16 rows, LDS dbuf.
// Per iter: scores(tt) | BAR | pack+write t(tt+1), issue loads t(tt+2) |
//           finish(tt) | PV(tt) | BAR.
// R13 change: staging pack uses v_cvt_pk_bf16_f32 (pk4) -- ~96 -> ~16 VALU
// per thread per tile; identical RNE rounding.
__global__ __launch_bounds__(512, 2)
void k_fused(const float* __restrict__ gr, const float* __restrict__ ws,
             float* __restrict__ attn_e, unsigned short* __restrict__ part,
             float* __restrict__ ssum) {
    extern __shared__ char smem[];
    const int b  = blockIdx.x >> 4;
    const int ck = blockIdx.x & 15;
    const int l0 = ck * CH;
    const int t  = threadIdx.x;
    const int wv = t >> 6, lane = t & 63;
    const int c16 = lane & 15, g = lane >> 4;
    const int estrip = wv * 128;            // this wave's e-strip

    // ---- prologue: pack r into B-frags (4 k-steps x 32 e), bias ----
    bf16x8 rpk[4];
#pragma unroll
    for (int ks = 0; ks < 4; ++ks) {
        const float* rp = ws + WS_R + (size_t)c16 * DD + estrip + ks * 32 + g * 8;
        float4 f0 = *(const float4*)rp, f1 = *(const float4*)(rp + 4);
        u16x4 lo = pk4(f0), hi = pk4(f1);
        bf16x8 r;
        r[0] = (short)lo[0]; r[1] = (short)lo[1]; r[2] = (short)lo[2]; r[3] = (short)lo[3];
        r[4] = (short)hi[0]; r[5] = (short)hi[1]; r[6] = (short)hi[2]; r[7] = (short)hi[3];
        rpk[ks] = r;
    }
    const float myc = (ws + WS_C)[c16];

    f32x4 pv[8];
#pragma unroll
    for (int i = 0; i < 8; ++i) pv[i] = (f32x4){0.f, 0.f, 0.f, 0.f};
    float s_acc = 0.f;

    // ---- staging geometry (conflict-free, 512 threads) ----
    const int srow = ((lane >> 2) & 3) + (wv & 3) * 4;   // row 0..15
    const int se0  = (lane & 3) * 4 + ((lane >> 4) + (wv >> 2) * 4) * 16;
    const float* gbase = gr + ((size_t)(b * LL + l0) + srow) * DD + se0;
    const int wr_base = ((lane >> 4) + (wv >> 2) * 4) * 512 + (wv & 3) * 128 +
                        ((lane >> 2) & 3) * 32 + (lane & 3) * 8;

    float4 raw[8];
    // tile 0: load + pack + write buf0
#pragma unroll
    for (int j = 0; j < 8; ++j) raw[j] = *(const float4*)(gbase + 128 * j);
#pragma unroll
    for (int j = 0; j < 8; ++j)
        *(u16x4*)(smem + wr_base + j * 4096) = pk4(raw[j]);
    // issue tile 1 loads
#pragma unroll
    for (int j = 0; j < 8; ++j)
        raw[j] = *(const float4*)(gbase + 16 * DD + 128 * j);
    __syncthreads();

#pragma unroll 1
    for (int tt = 0; tt < NT; ++tt) {
        const char* rb = smem + (tt & 1) * 32768;
        // ---- scores(tt): 4 k-steps over this wave's 128-e strip ----
        f32x4 sa = {0.f, 0.f, 0.f, 0.f};
#pragma unroll
        for (int ks = 0; ks < 4; ++ks) {
            const int e16 = wv * 8 + ks * 2 + (g >> 1);
            const int byt = (e16 * 4 + (c16 >> 2)) * 128 + (c16 & 3) * 32 + (g & 1) * 16;
            bf16x8 a = *(const bf16x8*)(rb + byt);
            sa = MFMA(a, rpk[ks], sa);
        }
        *(f32x4*)(smem + RED_OFF + (wv * 64 + lane) * 16) = sa;
        __syncthreads();                    // red visible; buf[(tt+1)&1] free
        // ---- stage tile tt+1 (pack from in-flight regs), issue tt+2 ----
        if (tt < NT - 1) {
            char* wb = smem + ((tt + 1) & 1) * 32768;
#pragma unroll
            for (int j = 0; j < 8; ++j)
                *(u16x4*)(wb + wr_base + j * 4096) = pk4(raw[j]);
            if (tt < NT - 2) {
                const float* gs = gbase + (size_t)(tt + 2) * 16 * DD;
#pragma unroll
                for (int j = 0; j < 8; ++j)
                    raw[j] = *(const float4*)(gs + 128 * j);
            }
        }
        // ---- finish(tt): sum 8 wave-partials + bias, exp ----
        f32x4 tot = {myc, myc, myc, myc};
#pragma unroll
        for (int w2 = 0; w2 < 8; ++w2)
            tot += *(const f32x4*)(smem + RED_OFF + (w2 * 64 + lane) * 16);
        f32x4 ex;                           // no max-shift: |score| ~ O(1)
        ex[0] = __expf(tot[0]); ex[1] = __expf(tot[1]);
        ex[2] = __expf(tot[2]); ex[3] = __expf(tot[3]);
        *(u16x4*)(smem + WT_OFF + wv * 512 + c16 * 32 + g * 8) =
            pk4(make_float4(ex[0], ex[1], ex[2], ex[3]));
        if (wv == (tt & 7)) {               // attn store, rotated across waves
            float* ap = attn_e + ((size_t)b * HH + c16) * LL + l0 + tt * 16 + g * 4;
            *(float4*)ap = make_float4(ex[0], ex[1], ex[2], ex[3]);
        }
        s_acc += ex[0] + ex[1] + ex[2] + ex[3];
        // ---- PV(tt): A = wt (zero for k>=16 lanes), B = tr-reads of G ----
        bf16x8 afrag;
        if (g < 2) {
            afrag = *(const bf16x8*)(smem + WT_OFF + wv * 512 + c16 * 32 + g * 16);
        } else {
            afrag = (bf16x8){0, 0, 0, 0, 0, 0, 0, 0};
        }
#pragma unroll
        for (int grp = 0; grp < 2; ++grp) {
            u32x2 q[8];
#pragma unroll
            for (int n2 = 0; n2 < 4; ++n2) {
                const int est = wv * 8 + grp * 4 + n2;
                const unsigned ta = (unsigned)((tt & 1) * 32768 + est * 512 +
                                               (g & 1) * 256 + c16 * 8);
                asm volatile("ds_read_b64_tr_b16 %0, %1"
                             : "=v"(q[n2 * 2]) : "v"(ta));
                asm volatile("ds_read_b64_tr_b16 %0, %1 offset:128"
                             : "=v"(q[n2 * 2 + 1]) : "v"(ta));
            }
            asm volatile("s_waitcnt lgkmcnt(0)" ::: "memory");
            __builtin_amdgcn_sched_barrier(0);
#pragma unroll
            for (int n2 = 0; n2 < 4; ++n2) {
                union { unsigned u[4]; bf16x8 v; } bb;
                bb.u[0] = q[n2 * 2][0];     bb.u[1] = q[n2 * 2][1];
                bb.u[2] = q[n2 * 2 + 1][0]; bb.u[3] = q[n2 * 2 + 1][1];
                pv[grp * 4 + n2] = MFMA(afrag, bb.v, pv[grp * 4 + n2]);
            }
        }
        __syncthreads();                    // stage(tt+1) visible; red free
    }
    // ---- epilogue: ssum + partials (bf16) ----
    float sv = s_acc;                       // identical in all waves
    sv += __shfl_xor(sv, 16, 64);
    sv += __shfl_xor(sv, 32, 64);
    if (wv == 0 && lane < 16)
        ssum[((size_t)b * NCK + ck) * HH + c16] = sv;
    unsigned short* pp = part + ((size_t)b * NCK + ck) * (HH * DD);
#pragma unroll
    for (int nt = 0; nt < 8; ++nt) {
#pragma unroll
        for (int r2 = 0; r2 < 4; ++r2)
            pp[(size_t)(g * 4 + r2) * DD + estrip + nt * 16 + c16] = f2bf(pv[nt][r2]);
    }
}

// ---------------- combine + attn-normalize + Wv: ctx[b, h*64+j] ------------
__global__ void k_ctx(const float* __restrict__ ipw, const float* __restrict__ ipb,
                      const unsigned short* __restrict__ part,
                      const float* __restrict__ ssum,
                      float* __restrict__ attn_e, float* __restrict__ ctx) {
    const int bh = blockIdx.x, b = bh >> 4, h = bh & 15;   // 512 blocks
    const int t = threadIdx.x, w = t >> 6, lane = t & 63;  // 256
    float S = 0.f;
#pragma unroll
    for (int c = 0; c < NCK; ++c) S += ssum[((size_t)b * NCK + c) * HH + h];
    const float inv = 1.0f / S;
    float4* ar = (float4*)(attn_e + (size_t)bh * LL);
#pragma unroll
    for (int i = 0; i < 2; ++i) {
        float4 v = ar[t + 256 * i];
        v.x *= inv; v.y *= inv; v.z *= inv; v.w *= inv;
        ar[t + 256 * i] = v;
    }
    __shared__ float Xl[DD];
    float4 x = {0.f, 0.f, 0.f, 0.f};
#pragma unroll
    for (int c = 0; c < NCK; ++c) {
        u16x4 p = *(const u16x4*)(part + ((size_t)b * NCK + c) * (HH * DD) +
                                  (size_t)h * DD + t * 4);
        x.x += bf2f(p[0]); x.y += bf2f(p[1]);
        x.z += bf2f(p[2]); x.w += bf2f(p[3]);
    }
    float4 xs = {x.x * inv, x.y * inv, x.z * inv, x.w * inv};
    ((float4*)Xl)[t] = xs;
    __syncthreads();
    for (int jj = 0; jj < 16; ++jj) {
        const int j = w * 16 + jj;
        const float* row = ipw + (size_t)(2 * DD + h * DHH + j) * DD;
        float acc = 0.f;
#pragma unroll
        for (int it = 0; it < 4; ++it) {
            float4 a = ((const float4*)row)[lane + 64 * it];
            float4 p = ((const float4*)Xl)[lane + 64 * it];
            acc += a.x * p.x + a.y * p.y + a.z * p.z + a.w * p.w;
        }
        acc = wave_sum(acc);
        if (lane == 0) ctx[(size_t)b * DD + h * DHH + j] = acc + ipb[2 * DD + h * DHH + j];
    }
}

// ---------------- y[b, d'] = out_w[d',:]·ctx[b,:] + out_b ----------------
__global__ void k_y(const float* __restrict__ ow, const float* __restrict__ ob,
                    const float* __restrict__ ctx, float* __restrict__ y) {
    const int blk = blockIdx.x, b = blk >> 4, ch = blk & 15;  // 512 blocks
    const int t = threadIdx.x, w = t >> 6, lane = t & 63;     // 256
    __shared__ float Xl[DD];
    ((float4*)Xl)[t] = ((const float4*)(ctx + (size_t)b * DD))[t];
    __syncthreads();
    for (int jj = 0; jj < 16; ++jj) {
        const int d = ch * 64 + w * 16 + jj;
        const float* row = ow + (size_t)d * DD;
        float acc = 0.f;
#pragma unroll
        for (int it = 0; it < 4; ++it) {
            float4 a = ((const float4*)row)[lane + 64 * it];
            float4 p = ((const float4*)Xl)[lane + 64 * it];
            acc += a.x * p.x + a.y * p.y + a.z * p.z + a.w * p.w;
        }
        acc = wave_sum(acc);
        if (lane == 0) y[(size_t)b * DD + d] = acc + ob[d];
    }
}

// ---------------- final LN -> pooled output ----------------
__global__ void k_lnout(const float* __restrict__ y, const float* __restrict__ on_w,
                        const float* __restrict__ on_b, float* __restrict__ outp) {
    const int b = blockIdx.x, t = threadIdx.x;   // 32 blocks, 256 threads
    const float4 x = ((const float4*)(y + (size_t)b * DD))[t];
    float s  = x.x + x.y + x.z + x.w;
    float s2 = x.x * x.x + x.y * x.y + x.z * x.z + x.w * x.w;
    __shared__ float rs[4], rs2[4];
    s = wave_sum(s); s2 = wave_sum(s2);
    const int w = t >> 6, lane = t & 63;
    if (lane == 0) { rs[w] = s; rs2[w] = s2; }
    __syncthreads();
    s  = rs[0] + rs[1] + rs[2] + rs[3];
    s2 = rs2[0] + rs2[1] + rs2[2] + rs2[3];
    const float mu  = s * (1.0f / DD);
    const float var = s2 * (1.0f / DD) - mu * mu;
    const float rstd = rsqrtf(var + 1e-5f);
    const float4 w4 = ((const float4*)on_w)[t];
    const float4 b4 = ((const float4*)on_b)[t];
    float4 o;
    o.x = (x.x - mu) * rstd * w4.x + b4.x;
    o.y = (x.y - mu) * rstd * w4.y + b4.y;
    o.z = (x.z - mu) * rstd * w4.z + b4.z;
    o.w = (x.w - mu) * rstd * w4.w + b4.w;
    ((float4*)(outp + (size_t)b * DD))[t] = o;
}

extern "C" void kernel_launch(void* const* d_in, const int* in_sizes, int n_in,
                              void* d_out, int out_size, void* d_ws, size_t ws_size,
                              hipStream_t stream) {
    const float* gr   = (const float*)d_in[0];
    const float* sq   = (const float*)d_in[1];
    const float* qn_w = (const float*)d_in[2];
    const float* qn_b = (const float*)d_in[3];
    const float* ipw  = (const float*)d_in[4];
    const float* ipb  = (const float*)d_in[5];
    const float* ow   = (const float*)d_in[6];
    const float* ob   = (const float*)d_in[7];
    const float* on_w = (const float*)d_in[8];
    const float* on_b = (const float*)d_in[9];
    const int*   pos  = (const int*)d_in[10];

    float* out  = (float*)d_out;
    float* attn = out + BB * DD;           // output 1; holds exp(score) until k_ctx norms
    float* ws   = (float*)d_ws;
    unsigned short* part16 = (unsigned short*)(ws + WS_PART);

    hipFuncSetAttribute((const void*)k_fused,
                        hipFuncAttributeMaxDynamicSharedMemorySize, SMEM_BYTES);

    k_q<<<256, 256, 0, stream>>>(sq, qn_w, qn_b, pos, ipw, ipb, ws);
    k_r<<<256, 64, 0, stream>>>(ipw, ipb, ws);
    k_fused<<<BB * NCK, 512, SMEM_BYTES, stream>>>(gr, ws, attn,
                                                   part16, ws + WS_SSUM);
    k_ctx<<<BB * HH, 256, 0, stream>>>(ipw, ipb, part16, ws + WS_SSUM,
                                       attn, ws + WS_CTX);
    k_y<<<BB * 16, 256, 0, stream>>>(ow, ob, ws + WS_CTX, ws + WS_Y);
    k_lnout<<<BB, 256, 0, stream>>>(ws + WS_Y, on_w, on_b, out);
}

// Round 14
// 100.516 us; speedup vs baseline: 1.0777x; 1.0058x over previous
//
#include <hip/hip_runtime.h>
#include <hip/hip_bf16.h>
#include <math.h>

#define BB 32
#define LL 2048
#define DD 1024
#define HH 16
#define DHH 64
#define NCK 16         // chunks per batch
#define CH  128        // rows per chunk
#define NT  8          // 16-row tiles per chunk

// ---- ws layout (float offsets) ----
#define WS_Q     1024       // 1024
#define WS_R     2048       // 16*1024
#define WS_C     18432      // 64 (16 used)
#define WS_CTX   19008      // 32768
#define WS_Y     51776      // 32768
#define WS_SSUM  84544      // 32*16*16 = 8192
#define WS_PART  92736      // 32*16*16*1024 bf16 = 16 MB

// ---- k_fused dynamic LDS layout (bytes) ----
// G tile buffers: 2 x (16 rows x 1024 e bf16, [4 l][16 e]-subtiled) = 2x32768
//   byte(l,e) = (e>>4)*512 + (l>>2)*128 + (l&3)*32 + (e&15)*2
#define RED_OFF  65536      // 8 waves x 64 lanes x 4 f32 = 8192
#define WT_OFF   73728      // 8 waves x 16 h x 16 l bf16 = 4096
#define SMEM_BYTES 77824

typedef __attribute__((ext_vector_type(8))) short    bf16x8;
typedef __attribute__((ext_vector_type(4))) short    bf16x4;
typedef __attribute__((ext_vector_type(4))) float    f32x4;
typedef __attribute__((ext_vector_type(2))) unsigned u32x2;
typedef __attribute__((ext_vector_type(4))) unsigned short u16x4;

#define MFMA(a, b, c) __builtin_amdgcn_mfma_f32_16x16x32_bf16(a, b, c, 0, 0, 0)

#if defined(__has_builtin)
#if __has_builtin(__builtin_amdgcn_mfma_f32_16x16x16bf16_1k)
#define HAVE_MFMA16 1
#define MFMA16(a, b, c) __builtin_amdgcn_mfma_f32_16x16x16bf16_1k(a, b, c, 0, 0, 0)
#endif
#endif
#ifndef HAVE_MFMA16
#define HAVE_MFMA16 0
#endif

__device__ __forceinline__ unsigned short f2bf(float f) {   // RNE f32->bf16
    unsigned u = __float_as_uint(f);
    return (unsigned short)((u + 0x7FFFu + ((u >> 16) & 1u)) >> 16);
}
// hot-path pack: v_cvt_pk_bf16_f32 via builtin (same RNE as f2bf)
__device__ __forceinline__ u16x4 pk4(float4 f) {
    __hip_bfloat162 a = __float22bfloat162_rn(make_float2(f.x, f.y));
    __hip_bfloat162 b = __float22bfloat162_rn(make_float2(f.z, f.w));
    ushort2 ua = *reinterpret_cast<ushort2*>(&a);
    ushort2 ub = *reinterpret_cast<ushort2*>(&b);
    u16x4 r; r[0] = ua.x; r[1] = ua.y; r[2] = ub.x; r[3] = ub.y;
    return r;
}
__device__ __forceinline__ float bf2f(unsigned short u) {
    return __uint_as_float((unsigned)u << 16);
}
__device__ __forceinline__ float wave_sum(float v) {
#pragma unroll
    for (int s = 32; s >= 1; s >>= 1) v += __shfl_xor(v, s, 64);
    return v;
}

// ---------------- K1: q = Wq @ LN(sq[pos]) + bq  (LN fused, wave/output) ----
__global__ void k_q(const float* __restrict__ sq, const float* __restrict__ qn_w,
                    const float* __restrict__ qn_b, const int* __restrict__ pos,
                    const float* __restrict__ ipw, const float* __restrict__ ipb,
                    float* __restrict__ ws) {
    const int t = threadIdx.x;              // 256 threads
    const int w = t >> 6, lane = t & 63;
    __shared__ float q0s[DD];
    __shared__ float rs[4], rs2[4];
    {   // redundant per-block LN of the single query row (4 KB, L2-hot)
        const float4 x = ((const float4*)(sq + (size_t)pos[0] * DD))[t];
        float s  = x.x + x.y + x.z + x.w;
        float s2 = x.x * x.x + x.y * x.y + x.z * x.z + x.w * x.w;
        s = wave_sum(s); s2 = wave_sum(s2);
        if (lane == 0) { rs[w] = s; rs2[w] = s2; }
        __syncthreads();
        s  = rs[0] + rs[1] + rs[2] + rs[3];
        s2 = rs2[0] + rs2[1] + rs2[2] + rs2[3];
        const float mu  = s * (1.0f / DD);
        const float var = s2 * (1.0f / DD) - mu * mu;
        const float rstd = rsqrtf(var + 1e-5f);
        const float4 w4 = ((const float4*)qn_w)[t];
        const float4 b4 = ((const float4*)qn_b)[t];
        float4 o;
        o.x = (x.x - mu) * rstd * w4.x + b4.x;
        o.y = (x.y - mu) * rstd * w4.y + b4.y;
        o.z = (x.z - mu) * rstd * w4.z + b4.z;
        o.w = (x.w - mu) * rstd * w4.w + b4.w;
        ((float4*)q0s)[t] = o;
    }
    __syncthreads();
    const int d = blockIdx.x * 4 + w;       // 256 blocks * 4 waves = 1024 outputs
    const float* row = ipw + (size_t)d * DD;
    float acc = 0.f;
#pragma unroll
    for (int it = 0; it < 4; ++it) {
        float4 a = ((const float4*)row)[lane + 64 * it];
        float4 b = ((const float4*)q0s)[lane + 64 * it];
        acc += a.x * b.x + a.y * b.y + a.z * b.z + a.w * b.w;
    }
    acc = wave_sum(acc);
    if (lane == 0) (ws + WS_Q)[d] = acc + ipb[d];
}

// ------- K2: r_s[h,e] = scale * sum_j q[h,j] Wk[h*64+j, e]  (256 blocks) ----
__global__ void k_r(const float* __restrict__ ipw, const float* __restrict__ ipb,
                    float* __restrict__ ws) {
    const int h = blockIdx.x >> 4, s = blockIdx.x & 15;
    const int t = threadIdx.x;              // 64 threads
    const int e = s * 64 + t;
    const float* q = ws + WS_Q;
    const float* wk = ipw + (size_t)(DD + h * DHH) * DD;
    float acc = 0.f;
#pragma unroll 8
    for (int j = 0; j < DHH; ++j)
        acc += q[h * DHH + j] * wk[(size_t)j * DD + e];
    (ws + WS_R)[h * DD + e] = acc * 0.125f;
    if (s == 0) {
        float p = q[h * DHH + t] * ipb[DD + h * DHH + t];
        p = wave_sum(p);
        if (t == 0) (ws + WS_C)[h] = p * 0.125f;
    }
}

// ---------------- fused MFMA, software-pipelined, 8 waves --------------
// block = (b, 128-row chunk), 8 waves (512 thr); 8 tiles of 16 rows, LDS dbuf.
// Per iter: scores(tt) | BAR | pack+write t(tt+1), issue loads t(tt+2) |
//           finish(tt) | PV(tt) | BAR.
// R14: PV uses mfma_f32_16x16x16bf16_1k (k=16 == tile rows): 8 tr_reads +
//      1 drain + 8 MFMAs per tile (was 16 tr + 2 drains + 8 half-wasted x32).
//      A: m=c16 (h), k=g*4+i (l) = wt[h][l] u16x4;  B: n=c16 (e), k=g*4+i (l)
//      = one ds_read_b64_tr_b16 at est*512 + g*128 + c16*8.  C/D map unchanged.
__global__ __launch_bounds__(512, 2)
void k_fused(const float* __restrict__ gr, const float* __restrict__ ws,
             float* __restrict__ attn_e, unsigned short* __restrict__ part,
             float* __restrict__ ssum) {
    extern __shared__ char smem[];
    const int b  = blockIdx.x >> 4;
    const int ck = blockIdx.x & 15;
    const int l0 = ck * CH;
    const int t  = threadIdx.x;
    const int wv = t >> 6, lane = t & 63;
    const int c16 = lane & 15, g = lane >> 4;
    const int estrip = wv * 128;            // this wave's e-strip

    // ---- prologue: pack r into B-frags (4 k-steps x 32 e), bias ----
    bf16x8 rpk[4];
#pragma unroll
    for (int ks = 0; ks < 4; ++ks) {
        const float* rp = ws + WS_R + (size_t)c16 * DD + estrip + ks * 32 + g * 8;
        float4 f0 = *(const float4*)rp, f1 = *(const float4*)(rp + 4);
        u16x4 lo = pk4(f0), hi = pk4(f1);
        bf16x8 r;
        r[0] = (short)lo[0]; r[1] = (short)lo[1]; r[2] = (short)lo[2]; r[3] = (short)lo[3];
        r[4] = (short)hi[0]; r[5] = (short)hi[1]; r[6] = (short)hi[2]; r[7] = (short)hi[3];
        rpk[ks] = r;
    }
    const float myc = (ws + WS_C)[c16];

    f32x4 pv[8];
#pragma unroll
    for (int i = 0; i < 8; ++i) pv[i] = (f32x4){0.f, 0.f, 0.f, 0.f};
    float s_acc = 0.f;

    // ---- staging geometry (conflict-free, 512 threads) ----
    const int srow = ((lane >> 2) & 3) + (wv & 3) * 4;   // row 0..15
    const int se0  = (lane & 3) * 4 + ((lane >> 4) + (wv >> 2) * 4) * 16;
    const float* gbase = gr + ((size_t)(b * LL + l0) + srow) * DD + se0;
    const int wr_base = ((lane >> 4) + (wv >> 2) * 4) * 512 + (wv & 3) * 128 +
                        ((lane >> 2) & 3) * 32 + (lane & 3) * 8;

    float4 raw[8];
    // tile 0: load + pack + write buf0
#pragma unroll
    for (int j = 0; j < 8; ++j) raw[j] = *(const float4*)(gbase + 128 * j);
#pragma unroll
    for (int j = 0; j < 8; ++j)
        *(u16x4*)(smem + wr_base + j * 4096) = pk4(raw[j]);
    // issue tile 1 loads
#pragma unroll
    for (int j = 0; j < 8; ++j)
        raw[j] = *(const float4*)(gbase + 16 * DD + 128 * j);
    __syncthreads();

#pragma unroll 1
    for (int tt = 0; tt < NT; ++tt) {
        const char* rb = smem + (tt & 1) * 32768;
        // ---- scores(tt): 4 k-steps over this wave's 128-e strip ----
        f32x4 sa = {0.f, 0.f, 0.f, 0.f};
#pragma unroll
        for (int ks = 0; ks < 4; ++ks) {
            const int e16 = wv * 8 + ks * 2 + (g >> 1);
            const int byt = (e16 * 4 + (c16 >> 2)) * 128 + (c16 & 3) * 32 + (g & 1) * 16;
            bf16x8 a = *(const bf16x8*)(rb + byt);
            sa = MFMA(a, rpk[ks], sa);
        }
        *(f32x4*)(smem + RED_OFF + (wv * 64 + lane) * 16) = sa;
        __syncthreads();                    // red visible; buf[(tt+1)&1] free
        // ---- stage tile tt+1 (pack from in-flight regs), issue tt+2 ----
        if (tt < NT - 1) {
            char* wb = smem + ((tt + 1) & 1) * 32768;
#pragma unroll
            for (int j = 0; j < 8; ++j)
                *(u16x4*)(wb + wr_base + j * 4096) = pk4(raw[j]);
            if (tt < NT - 2) {
                const float* gs = gbase + (size_t)(tt + 2) * 16 * DD;
#pragma unroll
                for (int j = 0; j < 8; ++j)
                    raw[j] = *(const float4*)(gs + 128 * j);
            }
        }
        // ---- finish(tt): sum 8 wave-partials + bias, exp ----
        f32x4 tot = {myc, myc, myc, myc};
#pragma unroll
        for (int w2 = 0; w2 < 8; ++w2)
            tot += *(const f32x4*)(smem + RED_OFF + (w2 * 64 + lane) * 16);
        f32x4 ex;                           // no max-shift: |score| ~ O(1)
        ex[0] = __expf(tot[0]); ex[1] = __expf(tot[1]);
        ex[2] = __expf(tot[2]); ex[3] = __expf(tot[3]);
        *(u16x4*)(smem + WT_OFF + wv * 512 + c16 * 32 + g * 8) =
            pk4(make_float4(ex[0], ex[1], ex[2], ex[3]));
        if (wv == (tt & 7)) {               // attn store, rotated across waves
            float* ap = attn_e + ((size_t)b * HH + c16) * LL + l0 + tt * 16 + g * 4;
            *(float4*)ap = make_float4(ex[0], ex[1], ex[2], ex[3]);
        }
        s_acc += ex[0] + ex[1] + ex[2] + ex[3];
#if HAVE_MFMA16
        // ---- PV(tt) k=16: A = wt[h][l=g*4+i], B = 1 tr_read per n-tile ----
        bf16x4 afrag;
        {
            u16x4 aw = *(const u16x4*)(smem + WT_OFF + wv * 512 + c16 * 32 + g * 8);
            afrag[0] = (short)aw[0]; afrag[1] = (short)aw[1];
            afrag[2] = (short)aw[2]; afrag[3] = (short)aw[3];
        }
        {
            u32x2 q[8];
#pragma unroll
            for (int nt = 0; nt < 8; ++nt) {
                const int est = wv * 8 + nt;
                const unsigned ta = (unsigned)((tt & 1) * 32768 + est * 512 +
                                               g * 128 + c16 * 8);
                asm volatile("ds_read_b64_tr_b16 %0, %1"
                             : "=v"(q[nt]) : "v"(ta));
            }
            asm volatile("s_waitcnt lgkmcnt(0)" ::: "memory");
            __builtin_amdgcn_sched_barrier(0);
#pragma unroll
            for (int nt = 0; nt < 8; ++nt) {
                union { unsigned u[2]; bf16x4 v; } bb;
                bb.u[0] = q[nt][0]; bb.u[1] = q[nt][1];
                pv[nt] = MFMA16(afrag, bb.v, pv[nt]);
            }
        }
#else
        // ---- PV(tt) fallback: k=32 with zero-padded A (R13 path) ----
        bf16x8 afrag;
        if (g < 2) {
            afrag = *(const bf16x8*)(smem + WT_OFF + wv * 512 + c16 * 32 + g * 16);
        } else {
            afrag = (bf16x8){0, 0, 0, 0, 0, 0, 0, 0};
        }
#pragma unroll
        for (int grp = 0; grp < 2; ++grp) {
            u32x2 q[8];
#pragma unroll
            for (int n2 = 0; n2 < 4; ++n2) {
                const int est = wv * 8 + grp * 4 + n2;
                const unsigned ta = (unsigned)((tt & 1) * 32768 + est * 512 +
                                               (g & 1) * 256 + c16 * 8);
                asm volatile("ds_read_b64_tr_b16 %0, %1"
                             : "=v"(q[n2 * 2]) : "v"(ta));
                asm volatile("ds_read_b64_tr_b16 %0, %1 offset:128"
                             : "=v"(q[n2 * 2 + 1]) : "v"(ta));
            }
            asm volatile("s_waitcnt lgkmcnt(0)" ::: "memory");
            __builtin_amdgcn_sched_barrier(0);
#pragma unroll
            for (int n2 = 0; n2 < 4; ++n2) {
                union { unsigned u[4]; bf16x8 v; } bb;
                bb.u[0] = q[n2 * 2][0];     bb.u[1] = q[n2 * 2][1];
                bb.u[2] = q[n2 * 2 + 1][0]; bb.u[3] = q[n2 * 2 + 1][1];
                pv[grp * 4 + n2] = MFMA(afrag, bb.v, pv[grp * 4 + n2]);
            }
        }
#endif
        __syncthreads();                    // stage(tt+1) visible; red free
    }
    // ---- epilogue: ssum + partials (bf16) ----
    float sv = s_acc;                       // identical in all waves
    sv += __shfl_xor(sv, 16, 64);
    sv += __shfl_xor(sv, 32, 64);
    if (wv == 0 && lane < 16)
        ssum[((size_t)b * NCK + ck) * HH + c16] = sv;
    unsigned short* pp = part + ((size_t)b * NCK + ck) * (HH * DD);
#pragma unroll
    for (int nt = 0; nt < 8; ++nt) {
#pragma unroll
        for (int r2 = 0; r2 < 4; ++r2)
            pp[(size_t)(g * 4 + r2) * DD + estrip + nt * 16 + c16] = f2bf(pv[nt][r2]);
    }
}

// ---------------- combine + attn-normalize + Wv: ctx[b, h*64+j] ------------
__global__ void k_ctx(const float* __restrict__ ipw, const float* __restrict__ ipb,
                      const unsigned short* __restrict__ part,
                      const float* __restrict__ ssum,
                      float* __restrict__ attn_e, float* __restrict__ ctx) {
    const int bh = blockIdx.x, b = bh >> 4, h = bh & 15;   // 512 blocks
    const int t = threadIdx.x, w = t >> 6, lane = t & 63;  // 256
    float S = 0.f;
#pragma unroll
    for (int c = 0; c < NCK; ++c) S += ssum[((size_t)b * NCK + c) * HH + h];
    const float inv = 1.0f / S;
    float4* ar = (float4*)(attn_e + (size_t)bh * LL);
#pragma unroll
    for (int i = 0; i < 2; ++i) {
        float4 v = ar[t + 256 * i];
        v.x *= inv; v.y *= inv; v.z *= inv; v.w *= inv;
        ar[t + 256 * i] = v;
    }
    __shared__ float Xl[DD];
    float4 x = {0.f, 0.f, 0.f, 0.f};
#pragma unroll
    for (int c = 0; c < NCK; ++c) {
        u16x4 p = *(const u16x4*)(part + ((size_t)b * NCK + c) * (HH * DD) +
                                  (size_t)h * DD + t * 4);
        x.x += bf2f(p[0]); x.y += bf2f(p[1]);
        x.z += bf2f(p[2]); x.w += bf2f(p[3]);
    }
    float4 xs = {x.x * inv, x.y * inv, x.z * inv, x.w * inv};
    ((float4*)Xl)[t] = xs;
    __syncthreads();
    for (int jj = 0; jj < 16; ++jj) {
        const int j = w * 16 + jj;
        const float* row = ipw + (size_t)(2 * DD + h * DHH + j) * DD;
        float acc = 0.f;
#pragma unroll
        for (int it = 0; it < 4; ++it) {
            float4 a = ((const float4*)row)[lane + 64 * it];
            float4 p = ((const float4*)Xl)[lane + 64 * it];
            acc += a.x * p.x + a.y * p.y + a.z * p.z + a.w * p.w;
        }
        acc = wave_sum(acc);
        if (lane == 0) ctx[(size_t)b * DD + h * DHH + j] = acc + ipb[2 * DD + h * DHH + j];
    }
}

// ---------------- y[b, d'] = out_w[d',:]·ctx[b,:] + out_b ----------------
__global__ void k_y(const float* __restrict__ ow, const float* __restrict__ ob,
                    const float* __restrict__ ctx, float* __restrict__ y) {
    const int blk = blockIdx.x, b = blk >> 4, ch = blk & 15;  // 512 blocks
    const int t = threadIdx.x, w = t >> 6, lane = t & 63;     // 256
    __shared__ float Xl[DD];
    ((float4*)Xl)[t] = ((const float4*)(ctx + (size_t)b * DD))[t];
    __syncthreads();
    for (int jj = 0; jj < 16; ++jj) {
        const int d = ch * 64 + w * 16 + jj;
        const float* row = ow + (size_t)d * DD;
        float acc = 0.f;
#pragma unroll
        for (int it = 0; it < 4; ++it) {
            float4 a = ((const float4*)row)[lane + 64 * it];
            float4 p = ((const float4*)Xl)[lane + 64 * it];
            acc += a.x * p.x + a.y * p.y + a.z * p.z + a.w * p.w;
        }
        acc = wave_sum(acc);
        if (lane == 0) y[(size_t)b * DD + d] = acc + ob[d];
    }
}

// ---------------- final LN -> pooled output ----------------
__global__ void k_lnout(const float* __restrict__ y, const float* __restrict__ on_w,
                        const float* __restrict__ on_b, float* __restrict__ outp) {
    const int b = blockIdx.x, t = threadIdx.x;   // 32 blocks, 256 threads
    const float4 x = ((const float4*)(y + (size_t)b * DD))[t];
    float s  = x.x + x.y + x.z + x.w;
    float s2 = x.x * x.x + x.y * x.y + x.z * x.z + x.w * x.w;
    __shared__ float rs[4], rs2[4];
    s = wave_sum(s); s2 = wave_sum(s2);
    const int w = t >> 6, lane = t & 63;
    if (lane == 0) { rs[w] = s; rs2[w] = s2; }
    __syncthreads();
    s  = rs[0] + rs[1] + rs[2] + rs[3];
    s2 = rs2[0] + rs2[1] + rs2[2] + rs2[3];
    const float mu  = s * (1.0f / DD);
    const float var = s2 * (1.0f / DD) - mu * mu;
    const float rstd = rsqrtf(var + 1e-5f);
    const float4 w4 = ((const float4*)on_w)[t];
    const float4 b4 = ((const float4*)on_b)[t];
    float4 o;
    o.x = (x.x - mu) * rstd * w4.x + b4.x;
    o.y = (x.y - mu) * rstd * w4.y + b4.y;
    o.z = (x.z - mu) * rstd * w4.z + b4.z;
    o.w = (x.w - mu) * rstd * w4.w + b4.w;
    ((float4*)(outp + (size_t)b * DD))[t] = o;
}

extern "C" void kernel_launch(void* const* d_in, const int* in_sizes, int n_in,
                              void* d_out, int out_size, void* d_ws, size_t ws_size,
                              hipStream_t stream) {
    const float* gr   = (const float*)d_in[0];
    const float* sq   = (const float*)d_in[1];
    const float* qn_w = (const float*)d_in[2];
    const float* qn_b = (const float*)d_in[3];
    const float* ipw  = (const float*)d_in[4];
    const float* ipb  = (const float*)d_in[5];
    const float* ow   = (const float*)d_in[6];
    const float* ob   = (const float*)d_in[7];
    const float* on_w = (const float*)d_in[8];
    const float* on_b = (const float*)d_in[9];
    const int*   pos  = (const int*)d_in[10];

    float* out  = (float*)d_out;
    float* attn = out + BB * DD;           // output 1; holds exp(score) until k_ctx norms
    float* ws   = (float*)d_ws;
    unsigned short* part16 = (unsigned short*)(ws + WS_PART);

    hipFuncSetAttribute((const void*)k_fused,
                        hipFuncAttributeMaxDynamicSharedMemorySize, SMEM_BYTES);

    k_q<<<256, 256, 0, stream>>>(sq, qn_w, qn_b, pos, ipw, ipb, ws);
    k_r<<<256, 64, 0, stream>>>(ipw, ipb, ws);
    k_fused<<<BB * NCK, 512, SMEM_BYTES, stream>>>(gr, ws, attn,
                                                   part16, ws + WS_SSUM);
    k_ctx<<<BB * HH, 256, 0, stream>>>(ipw, ipb, part16, ws + WS_SSUM,
                                       attn, ws + WS_CTX);
    k_y<<<BB * 16, 256, 0, stream>>>(ow, ob, ws + WS_CTX, ws + WS_Y);
    k_lnout<<<BB, 256, 0, stream>>>(ws + WS_Y, on_w, on_b, out);
}

// Round 15
// 100.104 us; speedup vs baseline: 1.0822x; 1.0041x over previous
//
#include <hip/hip_runtime.h>
#include <hip/hip_bf16.h>
#include <math.h>

#define BB 32
#define LL 2048
#define DD 1024
#define HH 16
#define DHH 64
#define NCK 16         // chunks per batch
#define CH  128        // rows per chunk
#define NT  8          // 16-row tiles per chunk

// ---- ws layout (float offsets) ----
#define WS_Q     1024       // 1024
#define WS_R     2048       // 16*1024
#define WS_C     18432      // 64 (16 used)
#define WS_CTX   19008      // 32768
#define WS_Y     51776      // 32768
#define WS_SSUM  84544      // 32*16*16 = 8192
#define WS_PART  92736      // 32*16*16*1024 bf16 = 16 MB

// ---- k_fused dynamic LDS layout (bytes) ----
// G tile buffers: 2 x (16 rows x 1024 e bf16, [4 l][16 e]-subtiled) = 2x32768
//   byte(l,e) = (e>>4)*512 + (l>>2)*128 + (l&3)*32 + (e&15)*2
#define RED_OFF  65536      // 8 waves x 64 lanes x 4 f32 = 8192
#define WT_OFF   73728      // 8 waves x 16 h x 16 l bf16 = 4096
#define SMEM_BYTES 77824

typedef __attribute__((ext_vector_type(8))) short    bf16x8;
typedef __attribute__((ext_vector_type(4))) short    bf16x4;
typedef __attribute__((ext_vector_type(4))) float    f32x4;
typedef __attribute__((ext_vector_type(2))) unsigned u32x2;
typedef __attribute__((ext_vector_type(4))) unsigned short u16x4;

#define MFMA(a, b, c) __builtin_amdgcn_mfma_f32_16x16x32_bf16(a, b, c, 0, 0, 0)

#if defined(__has_builtin)
#if __has_builtin(__builtin_amdgcn_mfma_f32_16x16x16bf16_1k)
#define HAVE_MFMA16 1
#define MFMA16(a, b, c) __builtin_amdgcn_mfma_f32_16x16x16bf16_1k(a, b, c, 0, 0, 0)
#endif
#endif
#ifndef HAVE_MFMA16
#define HAVE_MFMA16 0
#endif

__device__ __forceinline__ unsigned short f2bf(float f) {   // RNE f32->bf16
    unsigned u = __float_as_uint(f);
    return (unsigned short)((u + 0x7FFFu + ((u >> 16) & 1u)) >> 16);
}
// hot-path pack: v_cvt_pk_bf16_f32 via builtin (same RNE as f2bf)
__device__ __forceinline__ u16x4 pk4(float4 f) {
    __hip_bfloat162 a = __float22bfloat162_rn(make_float2(f.x, f.y));
    __hip_bfloat162 b = __float22bfloat162_rn(make_float2(f.z, f.w));
    ushort2 ua = *reinterpret_cast<ushort2*>(&a);
    ushort2 ub = *reinterpret_cast<ushort2*>(&b);
    u16x4 r; r[0] = ua.x; r[1] = ua.y; r[2] = ub.x; r[3] = ub.y;
    return r;
}
__device__ __forceinline__ float bf2f(unsigned short u) {
    return __uint_as_float((unsigned)u << 16);
}
__device__ __forceinline__ float wave_sum(float v) {
#pragma unroll
    for (int s = 32; s >= 1; s >>= 1) v += __shfl_xor(v, s, 64);
    return v;
}

// ---------------- K1: q = Wq @ LN(sq[pos]) + bq  (LN fused, wave/output) ----
__global__ void k_q(const float* __restrict__ sq, const float* __restrict__ qn_w,
                    const float* __restrict__ qn_b, const int* __restrict__ pos,
                    const float* __restrict__ ipw, const float* __restrict__ ipb,
                    float* __restrict__ ws) {
    const int t = threadIdx.x;              // 256 threads
    const int w = t >> 6, lane = t & 63;
    __shared__ float q0s[DD];
    __shared__ float rs[4], rs2[4];
    {   // redundant per-block LN of the single query row (4 KB, L2-hot)
        const float4 x = ((const float4*)(sq + (size_t)pos[0] * DD))[t];
        float s  = x.x + x.y + x.z + x.w;
        float s2 = x.x * x.x + x.y * x.y + x.z * x.z + x.w * x.w;
        s = wave_sum(s); s2 = wave_sum(s2);
        if (lane == 0) { rs[w] = s; rs2[w] = s2; }
        __syncthreads();
        s  = rs[0] + rs[1] + rs[2] + rs[3];
        s2 = rs2[0] + rs2[1] + rs2[2] + rs2[3];
        const float mu  = s * (1.0f / DD);
        const float var = s2 * (1.0f / DD) - mu * mu;
        const float rstd = rsqrtf(var + 1e-5f);
        const float4 w4 = ((const float4*)qn_w)[t];
        const float4 b4 = ((const float4*)qn_b)[t];
        float4 o;
        o.x = (x.x - mu) * rstd * w4.x + b4.x;
        o.y = (x.y - mu) * rstd * w4.y + b4.y;
        o.z = (x.z - mu) * rstd * w4.z + b4.z;
        o.w = (x.w - mu) * rstd * w4.w + b4.w;
        ((float4*)q0s)[t] = o;
    }
    __syncthreads();
    const int d = blockIdx.x * 4 + w;       // 256 blocks * 4 waves = 1024 outputs
    const float* row = ipw + (size_t)d * DD;
    float acc = 0.f;
#pragma unroll
    for (int it = 0; it < 4; ++it) {
        float4 a = ((const float4*)row)[lane + 64 * it];
        float4 b = ((const float4*)q0s)[lane + 64 * it];
        acc += a.x * b.x + a.y * b.y + a.z * b.z + a.w * b.w;
    }
    acc = wave_sum(acc);
    if (lane == 0) (ws + WS_Q)[d] = acc + ipb[d];
}

// ------- K2: r_s[h,e] = scale * sum_j q[h,j] Wk[h*64+j, e]  (256 blocks) ----
__global__ void k_r(const float* __restrict__ ipw, const float* __restrict__ ipb,
                    float* __restrict__ ws) {
    const int h = blockIdx.x >> 4, s = blockIdx.x & 15;
    const int t = threadIdx.x;              // 64 threads
    const int e = s * 64 + t;
    const float* q = ws + WS_Q;
    const float* wk = ipw + (size_t)(DD + h * DHH) * DD;
    float acc = 0.f;
#pragma unroll 8
    for (int j = 0; j < DHH; ++j)
        acc += q[h * DHH + j] * wk[(size_t)j * DD + e];
    (ws + WS_R)[h * DD + e] = acc * 0.125f;
    if (s == 0) {
        float p = q[h * DHH + t] * ipb[DD + h * DHH + t];
        p = wave_sum(p);
        if (t == 0) (ws + WS_C)[h] = p * 0.125f;
    }
}

// ---------------- fused MFMA, software-pipelined, 8 waves --------------
// block = (b, 128-row chunk), 8 waves (512 thr); 8 tiles of 16 rows, LDS dbuf.
// Per iter: scores(tt) | BAR | pack+write t(tt+1), issue loads t(tt+2) |
//           finish(tt) | PV(tt) | BAR.
// R15: __launch_bounds__(512, 4) = min 4 waves/SIMD -> VGPR capped at 128 so
//      TWO 512-thr blocks co-reside per CU (LDS 2x76KB <= 160KB). Cross-block
//      overlap hides the barrier-serialized phases. Worst case is a ~10-reg
//      trim (mild), unlike R3's 64-reg clamp disaster.
__global__ __launch_bounds__(512, 4)
void k_fused(const float* __restrict__ gr, const float* __restrict__ ws,
             float* __restrict__ attn_e, unsigned short* __restrict__ part,
             float* __restrict__ ssum) {
    extern __shared__ char smem[];
    const int b  = blockIdx.x >> 4;
    const int ck = blockIdx.x & 15;
    const int l0 = ck * CH;
    const int t  = threadIdx.x;
    const int wv = t >> 6, lane = t & 63;
    const int c16 = lane & 15, g = lane >> 4;
    const int estrip = wv * 128;            // this wave's e-strip

    // ---- prologue: pack r into B-frags (4 k-steps x 32 e), bias ----
    bf16x8 rpk[4];
#pragma unroll
    for (int ks = 0; ks < 4; ++ks) {
        const float* rp = ws + WS_R + (size_t)c16 * DD + estrip + ks * 32 + g * 8;
        float4 f0 = *(const float4*)rp, f1 = *(const float4*)(rp + 4);
        u16x4 lo = pk4(f0), hi = pk4(f1);
        bf16x8 r;
        r[0] = (short)lo[0]; r[1] = (short)lo[1]; r[2] = (short)lo[2]; r[3] = (short)lo[3];
        r[4] = (short)hi[0]; r[5] = (short)hi[1]; r[6] = (short)hi[2]; r[7] = (short)hi[3];
        rpk[ks] = r;
    }
    const float myc = (ws + WS_C)[c16];

    f32x4 pv[8];
#pragma unroll
    for (int i = 0; i < 8; ++i) pv[i] = (f32x4){0.f, 0.f, 0.f, 0.f};
    float s_acc = 0.f;

    // ---- staging geometry (conflict-free, 512 threads) ----
    const int srow = ((lane >> 2) & 3) + (wv & 3) * 4;   // row 0..15
    const int se0  = (lane & 3) * 4 + ((lane >> 4) + (wv >> 2) * 4) * 16;
    const float* gbase = gr + ((size_t)(b * LL + l0) + srow) * DD + se0;
    const int wr_base = ((lane >> 4) + (wv >> 2) * 4) * 512 + (wv & 3) * 128 +
                        ((lane >> 2) & 3) * 32 + (lane & 3) * 8;

    float4 raw[8];
    // tile 0: load + pack + write buf0
#pragma unroll
    for (int j = 0; j < 8; ++j) raw[j] = *(const float4*)(gbase + 128 * j);
#pragma unroll
    for (int j = 0; j < 8; ++j)
        *(u16x4*)(smem + wr_base + j * 4096) = pk4(raw[j]);
    // issue tile 1 loads
#pragma unroll
    for (int j = 0; j < 8; ++j)
        raw[j] = *(const float4*)(gbase + 16 * DD + 128 * j);
    __syncthreads();

#pragma unroll 1
    for (int tt = 0; tt < NT; ++tt) {
        const char* rb = smem + (tt & 1) * 32768;
        // ---- scores(tt): 4 k-steps over this wave's 128-e strip ----
        f32x4 sa = {0.f, 0.f, 0.f, 0.f};
#pragma unroll
        for (int ks = 0; ks < 4; ++ks) {
            const int e16 = wv * 8 + ks * 2 + (g >> 1);
            const int byt = (e16 * 4 + (c16 >> 2)) * 128 + (c16 & 3) * 32 + (g & 1) * 16;
            bf16x8 a = *(const bf16x8*)(rb + byt);
            sa = MFMA(a, rpk[ks], sa);
        }
        *(f32x4*)(smem + RED_OFF + (wv * 64 + lane) * 16) = sa;
        __syncthreads();                    // red visible; buf[(tt+1)&1] free
        // ---- stage tile tt+1 (pack from in-flight regs), issue tt+2 ----
        if (tt < NT - 1) {
            char* wb = smem + ((tt + 1) & 1) * 32768;
#pragma unroll
            for (int j = 0; j < 8; ++j)
                *(u16x4*)(wb + wr_base + j * 4096) = pk4(raw[j]);
            if (tt < NT - 2) {
                const float* gs = gbase + (size_t)(tt + 2) * 16 * DD;
#pragma unroll
                for (int j = 0; j < 8; ++j)
                    raw[j] = *(const float4*)(gs + 128 * j);
            }
        }
        // ---- finish(tt): sum 8 wave-partials + bias, exp ----
        f32x4 tot = {myc, myc, myc, myc};
#pragma unroll
        for (int w2 = 0; w2 < 8; ++w2)
            tot += *(const f32x4*)(smem + RED_OFF + (w2 * 64 + lane) * 16);
        f32x4 ex;                           // no max-shift: |score| ~ O(1)
        ex[0] = __expf(tot[0]); ex[1] = __expf(tot[1]);
        ex[2] = __expf(tot[2]); ex[3] = __expf(tot[3]);
        *(u16x4*)(smem + WT_OFF + wv * 512 + c16 * 32 + g * 8) =
            pk4(make_float4(ex[0], ex[1], ex[2], ex[3]));
        if (wv == (tt & 7)) {               // attn store, rotated across waves
            float* ap = attn_e + ((size_t)b * HH + c16) * LL + l0 + tt * 16 + g * 4;
            *(float4*)ap = make_float4(ex[0], ex[1], ex[2], ex[3]);
        }
        s_acc += ex[0] + ex[1] + ex[2] + ex[3];
#if HAVE_MFMA16
        // ---- PV(tt) k=16: A = wt[h][l=g*4+i], B = 1 tr_read per n-tile ----
        bf16x4 afrag;
        {
            u16x4 aw = *(const u16x4*)(smem + WT_OFF + wv * 512 + c16 * 32 + g * 8);
            afrag[0] = (short)aw[0]; afrag[1] = (short)aw[1];
            afrag[2] = (short)aw[2]; afrag[3] = (short)aw[3];
        }
        {
            u32x2 q[8];
#pragma unroll
            for (int nt = 0; nt < 8; ++nt) {
                const int est = wv * 8 + nt;
                const unsigned ta = (unsigned)((tt & 1) * 32768 + est * 512 +
                                               g * 128 + c16 * 8);
                asm volatile("ds_read_b64_tr_b16 %0, %1"
                             : "=v"(q[nt]) : "v"(ta));
            }
            asm volatile("s_waitcnt lgkmcnt(0)" ::: "memory");
            __builtin_amdgcn_sched_barrier(0);
#pragma unroll
            for (int nt = 0; nt < 8; ++nt) {
                union { unsigned u[2]; bf16x4 v; } bb;
                bb.u[0] = q[nt][0]; bb.u[1] = q[nt][1];
                pv[nt] = MFMA16(afrag, bb.v, pv[nt]);
            }
        }
#else
        // ---- PV(tt) fallback: k=32 with zero-padded A (R13 path) ----
        bf16x8 afrag;
        if (g < 2) {
            afrag = *(const bf16x8*)(smem + WT_OFF + wv * 512 + c16 * 32 + g * 16);
        } else {
            afrag = (bf16x8){0, 0, 0, 0, 0, 0, 0, 0};
        }
#pragma unroll
        for (int grp = 0; grp < 2; ++grp) {
            u32x2 q[8];
#pragma unroll
            for (int n2 = 0; n2 < 4; ++n2) {
                const int est = wv * 8 + grp * 4 + n2;
                const unsigned ta = (unsigned)((tt & 1) * 32768 + est * 512 +
                                               (g & 1) * 256 + c16 * 8);
                asm volatile("ds_read_b64_tr_b16 %0, %1"
                             : "=v"(q[n2 * 2]) : "v"(ta));
                asm volatile("ds_read_b64_tr_b16 %0, %1 offset:128"
                             : "=v"(q[n2 * 2 + 1]) : "v"(ta));
            }
            asm volatile("s_waitcnt lgkmcnt(0)" ::: "memory");
            __builtin_amdgcn_sched_barrier(0);
#pragma unroll
            for (int n2 = 0; n2 < 4; ++n2) {
                union { unsigned u[4]; bf16x8 v; } bb;
                bb.u[0] = q[n2 * 2][0];     bb.u[1] = q[n2 * 2][1];
                bb.u[2] = q[n2 * 2 + 1][0]; bb.u[3] = q[n2 * 2 + 1][1];
                pv[grp * 4 + n2] = MFMA(afrag, bb.v, pv[grp * 4 + n2]);
            }
        }
#endif
        __syncthreads();                    // stage(tt+1) visible; red free
    }
    // ---- epilogue: ssum + partials (bf16) ----
    float sv = s_acc;                       // identical in all waves
    sv += __shfl_xor(sv, 16, 64);
    sv += __shfl_xor(sv, 32, 64);
    if (wv == 0 && lane < 16)
        ssum[((size_t)b * NCK + ck) * HH + c16] = sv;
    unsigned short* pp = part + ((size_t)b * NCK + ck) * (HH * DD);
#pragma unroll
    for (int nt = 0; nt < 8; ++nt) {
#pragma unroll
        for (int r2 = 0; r2 < 4; ++r2)
            pp[(size_t)(g * 4 + r2) * DD + estrip + nt * 16 + c16] = f2bf(pv[nt][r2]);
    }
}

// ---------------- combine + attn-normalize + Wv: ctx[b, h*64+j] ------------
__global__ void k_ctx(const float* __restrict__ ipw, const float* __restrict__ ipb,
                      const unsigned short* __restrict__ part,
                      const float* __restrict__ ssum,
                      float* __restrict__ attn_e, float* __restrict__ ctx) {
    const int bh = blockIdx.x, b = bh >> 4, h = bh & 15;   // 512 blocks
    const int t = threadIdx.x, w = t >> 6, lane = t & 63;  // 256
    float S = 0.f;
#pragma unroll
    for (int c = 0; c < NCK; ++c) S += ssum[((size_t)b * NCK + c) * HH + h];
    const float inv = 1.0f / S;
    float4* ar = (float4*)(attn_e + (size_t)bh * LL);
#pragma unroll
    for (int i = 0; i < 2; ++i) {
        float4 v = ar[t + 256 * i];
        v.x *= inv; v.y *= inv; v.z *= inv; v.w *= inv;
        ar[t + 256 * i] = v;
    }
    __shared__ float Xl[DD];
    float4 x = {0.f, 0.f, 0.f, 0.f};
#pragma unroll
    for (int c = 0; c < NCK; ++c) {
        u16x4 p = *(const u16x4*)(part + ((size_t)b * NCK + c) * (HH * DD) +
                                  (size_t)h * DD + t * 4);
        x.x += bf2f(p[0]); x.y += bf2f(p[1]);
        x.z += bf2f(p[2]); x.w += bf2f(p[3]);
    }
    float4 xs = {x.x * inv, x.y * inv, x.z * inv, x.w * inv};
    ((float4*)Xl)[t] = xs;
    __syncthreads();
    for (int jj = 0; jj < 16; ++jj) {
        const int j = w * 16 + jj;
        const float* row = ipw + (size_t)(2 * DD + h * DHH + j) * DD;
        float acc = 0.f;
#pragma unroll
        for (int it = 0; it < 4; ++it) {
            float4 a = ((const float4*)row)[lane + 64 * it];
            float4 p = ((const float4*)Xl)[lane + 64 * it];
            acc += a.x * p.x + a.y * p.y + a.z * p.z + a.w * p.w;
        }
        acc = wave_sum(acc);
        if (lane == 0) ctx[(size_t)b * DD + h * DHH + j] = acc + ipb[2 * DD + h * DHH + j];
    }
}

// ---------------- y[b, d'] = out_w[d',:]·ctx[b,:] + out_b ----------------
__global__ void k_y(const float* __restrict__ ow, const float* __restrict__ ob,
                    const float* __restrict__ ctx, float* __restrict__ y) {
    const int blk = blockIdx.x, b = blk >> 4, ch = blk & 15;  // 512 blocks
    const int t = threadIdx.x, w = t >> 6, lane = t & 63;     // 256
    __shared__ float Xl[DD];
    ((float4*)Xl)[t] = ((const float4*)(ctx + (size_t)b * DD))[t];
    __syncthreads();
    for (int jj = 0; jj < 16; ++jj) {
        const int d = ch * 64 + w * 16 + jj;
        const float* row = ow + (size_t)d * DD;
        float acc = 0.f;
#pragma unroll
        for (int it = 0; it < 4; ++it) {
            float4 a = ((const float4*)row)[lane + 64 * it];
            float4 p = ((const float4*)Xl)[lane + 64 * it];
            acc += a.x * p.x + a.y * p.y + a.z * p.z + a.w * p.w;
        }
        acc = wave_sum(acc);
        if (lane == 0) y[(size_t)b * DD + d] = acc + ob[d];
    }
}

// ---------------- final LN -> pooled output ----------------
__global__ void k_lnout(const float* __restrict__ y, const float* __restrict__ on_w,
                        const float* __restrict__ on_b, float* __restrict__ outp) {
    const int b = blockIdx.x, t = threadIdx.x;   // 32 blocks, 256 threads
    const float4 x = ((const float4*)(y + (size_t)b * DD))[t];
    float s  = x.x + x.y + x.z + x.w;
    float s2 = x.x * x.x + x.y * x.y + x.z * x.z + x.w * x.w;
    __shared__ float rs[4], rs2[4];
    s = wave_sum(s); s2 = wave_sum(s2);
    const int w = t >> 6, lane = t & 63;
    if (lane == 0) { rs[w] = s; rs2[w] = s2; }
    __syncthreads();
    s  = rs[0] + rs[1] + rs[2] + rs[3];
    s2 = rs2[0] + rs2[1] + rs2[2] + rs2[3];
    const float mu  = s * (1.0f / DD);
    const float var = s2 * (1.0f / DD) - mu * mu;
    const float rstd = rsqrtf(var + 1e-5f);
    const float4 w4 = ((const float4*)on_w)[t];
    const float4 b4 = ((const float4*)on_b)[t];
    float4 o;
    o.x = (x.x - mu) * rstd * w4.x + b4.x;
    o.y = (x.y - mu) * rstd * w4.y + b4.y;
    o.z = (x.z - mu) * rstd * w4.z + b4.z;
    o.w = (x.w - mu) * rstd * w4.w + b4.w;
    ((float4*)(outp + (size_t)b * DD))[t] = o;
}

extern "C" void kernel_launch(void* const* d_in, const int* in_sizes, int n_in,
                              void* d_out, int out_size, void* d_ws, size_t ws_size,
                              hipStream_t stream) {
    const float* gr   = (const float*)d_in[0];
    const float* sq   = (const float*)d_in[1];
    const float* qn_w = (const float*)d_in[2];
    const float* qn_b = (const float*)d_in[3];
    const float* ipw  = (const float*)d_in[4];
    const float* ipb  = (const float*)d_in[5];
    const float* ow   = (const float*)d_in[6];
    const float* ob   = (const float*)d_in[7];
    const float* on_w = (const float*)d_in[8];
    const float* on_b = (const float*)d_in[9];
    const int*   pos  = (const int*)d_in[10];

    float* out  = (float*)d_out;
    float* attn = out + BB * DD;           // output 1; holds exp(score) until k_ctx norms
    float* ws   = (float*)d_ws;
    unsigned short* part16 = (unsigned short*)(ws + WS_PART);

    hipFuncSetAttribute((const void*)k_fused,
                        hipFuncAttributeMaxDynamicSharedMemorySize, SMEM_BYTES);

    k_q<<<256, 256, 0, stream>>>(sq, qn_w, qn_b, pos, ipw, ipb, ws);
    k_r<<<256, 64, 0, stream>>>(ipw, ipb, ws);
    k_fused<<<BB * NCK, 512, SMEM_BYTES, stream>>>(gr, ws, attn,
                                                   part16, ws + WS_SSUM);
    k_ctx<<<BB * HH, 256, 0, stream>>>(ipw, ipb, part16, ws + WS_SSUM,
                                       attn, ws + WS_CTX);
    k_y<<<BB * 16, 256, 0, stream>>>(ow, ob, ws + WS_CTX, ws + WS_Y);
    k_lnout<<<BB, 256, 0, stream>>>(ws + WS_Y, on_w, on_b, out);
}

// Round 16
// 99.691 us; speedup vs baseline: 1.0867x; 1.0041x over previous
//
#include <hip/hip_runtime.h>
#include <hip/hip_bf16.h>
#include <math.h>

#define BB 32
#define LL 2048
#define DD 1024
#define HH 16
#define DHH 64
#define NCK 16         // chunks per batch
#define CH  128        // rows per chunk
#define NT  8          // 16-row tiles per chunk

// ---- ws layout (float offsets) ----
#define WS_Q     1024       // 1024
#define WS_R     2048       // 16*1024
#define WS_C     18432      // 64 (16 used)
#define WS_CTX   19008      // 32768
#define WS_Y     51776      // 32768
#define WS_SSUM  84544      // 32*16*16 = 8192
#define WS_PART  92736      // 32*16*16*1024 bf16 = 16 MB

// ---- k_fused dynamic LDS layout (bytes) ----
// G tile buffers: 2 x (16 rows x 1024 e bf16, [4 l][16 e]-subtiled) = 2x32768
//   byte(l,e) = (e>>4)*512 + (l>>2)*128 + (l&3)*32 + (e&15)*2
//   R16: buf regions are WAVE-PRIVATE (wave wv owns e16 in [wv*8, wv*8+8))
// red: 2 x (8 waves x 64 lanes x u16x4 bf16) = 2 x 4096  (double-buffered)
#define RED_OFF  65536
#define WT_OFF   73728      // 8 waves x 16 h x 16 l bf16 = 4096
#define SMEM_BYTES 77824

typedef __attribute__((ext_vector_type(8))) short    bf16x8;
typedef __attribute__((ext_vector_type(4))) short    bf16x4;
typedef __attribute__((ext_vector_type(4))) float    f32x4;
typedef __attribute__((ext_vector_type(2))) unsigned u32x2;
typedef __attribute__((ext_vector_type(4))) unsigned short u16x4;

#define MFMA(a, b, c) __builtin_amdgcn_mfma_f32_16x16x32_bf16(a, b, c, 0, 0, 0)

#if defined(__has_builtin)
#if __has_builtin(__builtin_amdgcn_mfma_f32_16x16x16bf16_1k)
#define HAVE_MFMA16 1
#define MFMA16(a, b, c) __builtin_amdgcn_mfma_f32_16x16x16bf16_1k(a, b, c, 0, 0, 0)
#endif
#endif
#ifndef HAVE_MFMA16
#define HAVE_MFMA16 0
#endif

__device__ __forceinline__ unsigned short f2bf(float f) {   // RNE f32->bf16
    unsigned u = __float_as_uint(f);
    return (unsigned short)((u + 0x7FFFu + ((u >> 16) & 1u)) >> 16);
}
// hot-path pack: v_cvt_pk_bf16_f32 via builtin (same RNE as f2bf)
__device__ __forceinline__ u16x4 pk4(float4 f) {
    __hip_bfloat162 a = __float22bfloat162_rn(make_float2(f.x, f.y));
    __hip_bfloat162 b = __float22bfloat162_rn(make_float2(f.z, f.w));
    ushort2 ua = *reinterpret_cast<ushort2*>(&a);
    ushort2 ub = *reinterpret_cast<ushort2*>(&b);
    u16x4 r; r[0] = ua.x; r[1] = ua.y; r[2] = ub.x; r[3] = ub.y;
    return r;
}
__device__ __forceinline__ u16x4 pk4v(f32x4 f) {
    return pk4(make_float4(f[0], f[1], f[2], f[3]));
}
__device__ __forceinline__ float bf2f(unsigned short u) {
    return __uint_as_float((unsigned)u << 16);
}
__device__ __forceinline__ float wave_sum(float v) {
#pragma unroll
    for (int s = 32; s >= 1; s >>= 1) v += __shfl_xor(v, s, 64);
    return v;
}

// ---------------- K1: q = Wq @ LN(sq[pos]) + bq  (LN fused, wave/output) ----
__global__ void k_q(const float* __restrict__ sq, const float* __restrict__ qn_w,
                    const float* __restrict__ qn_b, const int* __restrict__ pos,
                    const float* __restrict__ ipw, const float* __restrict__ ipb,
                    float* __restrict__ ws) {
    const int t = threadIdx.x;              // 256 threads
    const int w = t >> 6, lane = t & 63;
    __shared__ float q0s[DD];
    __shared__ float rs[4], rs2[4];
    {   // redundant per-block LN of the single query row (4 KB, L2-hot)
        const float4 x = ((const float4*)(sq + (size_t)pos[0] * DD))[t];
        float s  = x.x + x.y + x.z + x.w;
        float s2 = x.x * x.x + x.y * x.y + x.z * x.z + x.w * x.w;
        s = wave_sum(s); s2 = wave_sum(s2);
        if (lane == 0) { rs[w] = s; rs2[w] = s2; }
        __syncthreads();
        s  = rs[0] + rs[1] + rs[2] + rs[3];
        s2 = rs2[0] + rs2[1] + rs2[2] + rs2[3];
        const float mu  = s * (1.0f / DD);
        const float var = s2 * (1.0f / DD) - mu * mu;
        const float rstd = rsqrtf(var + 1e-5f);
        const float4 w4 = ((const float4*)qn_w)[t];
        const float4 b4 = ((const float4*)qn_b)[t];
        float4 o;
        o.x = (x.x - mu) * rstd * w4.x + b4.x;
        o.y = (x.y - mu) * rstd * w4.y + b4.y;
        o.z = (x.z - mu) * rstd * w4.z + b4.z;
        o.w = (x.w - mu) * rstd * w4.w + b4.w;
        ((float4*)q0s)[t] = o;
    }
    __syncthreads();
    const int d = blockIdx.x * 4 + w;       // 256 blocks * 4 waves = 1024 outputs
    const float* row = ipw + (size_t)d * DD;
    float acc = 0.f;
#pragma unroll
    for (int it = 0; it < 4; ++it) {
        float4 a = ((const float4*)row)[lane + 64 * it];
        float4 b = ((const float4*)q0s)[lane + 64 * it];
        acc += a.x * b.x + a.y * b.y + a.z * b.z + a.w * b.w;
    }
    acc = wave_sum(acc);
    if (lane == 0) (ws + WS_Q)[d] = acc + ipb[d];
}

// ------- K2: r_s[h,e] = scale * sum_j q[h,j] Wk[h*64+j, e]  (256 blocks) ----
__global__ void k_r(const float* __restrict__ ipw, const float* __restrict__ ipb,
                    float* __restrict__ ws) {
    const int h = blockIdx.x >> 4, s = blockIdx.x & 15;
    const int t = threadIdx.x;              // 64 threads
    const int e = s * 64 + t;
    const float* q = ws + WS_Q;
    const float* wk = ipw + (size_t)(DD + h * DHH) * DD;
    float acc = 0.f;
#pragma unroll 8
    for (int j = 0; j < DHH; ++j)
        acc += q[h * DHH + j] * wk[(size_t)j * DD + e];
    (ws + WS_R)[h * DD + e] = acc * 0.125f;
    if (s == 0) {
        float p = q[h * DHH + t] * ipb[DD + h * DHH + t];
        p = wave_sum(p);
        if (t == 0) (ws + WS_C)[h] = p * 0.125f;
    }
}

// ---------------- fused MFMA, wave-local staging, ONE barrier/tile ---------
// block = (b, 128-row chunk), 8 waves (512 thr); 8 tiles of 16 rows.
// R16: each wave stages ITS OWN e-strip (16 rows x 128 e) -> G buffers are
//   wave-private; stage->scores and PV->overwrite are own-wave lgkm-ordered.
//   Only the cross-wave score reduction `red` needs sync: double-buffered
//   (bf16 to keep LDS at 77824 for 2-block/CU residency), 1 barrier/tile.
// Per iter: finish(tt) [red[tt&1]] | stage(tt+1)+issue(tt+2) | PV(tt) |
//           scores(tt+1)->red[(tt+1)&1] | BARRIER.
// Staging map (wave-local, conflict-free: byte%128 = 8*(lane&15)):
//   row = (lane>>4)*4 + ((lane>>2)&3);  e = wv*128 + (lane&3)*4 + 16*j
__global__ __launch_bounds__(512, 4)
void k_fused(const float* __restrict__ gr, const float* __restrict__ ws,
             float* __restrict__ attn_e, unsigned short* __restrict__ part,
             float* __restrict__ ssum) {
    extern __shared__ char smem[];
    const int b  = blockIdx.x >> 4;
    const int ck = blockIdx.x & 15;
    const int l0 = ck * CH;
    const int t  = threadIdx.x;
    const int wv = t >> 6, lane = t & 63;
    const int c16 = lane & 15, g = lane >> 4;
    const int estrip = wv * 128;            // this wave's e-strip

    // ---- prologue: pack r into B-frags (4 k-steps x 32 e), bias ----
    bf16x8 rpk[4];
#pragma unroll
    for (int ks = 0; ks < 4; ++ks) {
        const float* rp = ws + WS_R + (size_t)c16 * DD + estrip + ks * 32 + g * 8;
        float4 f0 = *(const float4*)rp, f1 = *(const float4*)(rp + 4);
        u16x4 lo = pk4(f0), hi = pk4(f1);
        bf16x8 r;
        r[0] = (short)lo[0]; r[1] = (short)lo[1]; r[2] = (short)lo[2]; r[3] = (short)lo[3];
        r[4] = (short)hi[0]; r[5] = (short)hi[1]; r[6] = (short)hi[2]; r[7] = (short)hi[3];
        rpk[ks] = r;
    }
    const float myc = (ws + WS_C)[c16];

    f32x4 pv[8];
#pragma unroll
    for (int i = 0; i < 8; ++i) pv[i] = (f32x4){0.f, 0.f, 0.f, 0.f};
    float s_acc = 0.f;

    // ---- wave-local staging geometry ----
    const int srow = (lane >> 4) * 4 + ((lane >> 2) & 3);   // row 0..15
    const float* gbase = gr + ((size_t)(b * LL + l0) + srow) * DD +
                         estrip + (lane & 3) * 4;
    const int wr_base = (wv * 8) * 512 + (lane >> 4) * 128 +
                        ((lane >> 2) & 3) * 32 + (lane & 3) * 8;

    // scores helper data layout (read own strip): e16 = wv*8 + ks*2 + (g>>1)
    // byt = (e16*4 + (c16>>2))*128 + (c16&3)*32 + (g&1)*16

    float4 raw[8];
    // tile 0: load + pack + write buf0 (own strip)
#pragma unroll
    for (int j = 0; j < 8; ++j) raw[j] = *(const float4*)(gbase + 16 * j);
#pragma unroll
    for (int j = 0; j < 8; ++j)
        *(u16x4*)(smem + wr_base + j * 512) = pk4(raw[j]);
    // issue tile 1 loads
#pragma unroll
    for (int j = 0; j < 8; ++j)
        raw[j] = *(const float4*)(gbase + 16 * DD + 16 * j);
    // scores(0) -> red[0]   (own-wave lgkm ordering covers stage->read)
    {
        f32x4 sa = {0.f, 0.f, 0.f, 0.f};
#pragma unroll
        for (int ks = 0; ks < 4; ++ks) {
            const int e16 = wv * 8 + ks * 2 + (g >> 1);
            const int byt = (e16 * 4 + (c16 >> 2)) * 128 + (c16 & 3) * 32 + (g & 1) * 16;
            bf16x8 a = *(const bf16x8*)(smem + byt);
            sa = MFMA(a, rpk[ks], sa);
        }
        *(u16x4*)(smem + RED_OFF + (wv * 64 + lane) * 8) = pk4v(sa);
    }
    __syncthreads();

#pragma unroll 1
    for (int tt = 0; tt < NT; ++tt) {
        // ---- finish(tt): sum 8 bf16 wave-partials + bias, exp ----
        f32x4 tot = {myc, myc, myc, myc};
#pragma unroll
        for (int w2 = 0; w2 < 8; ++w2) {
            u16x4 p = *(const u16x4*)(smem + RED_OFF + (tt & 1) * 4096 +
                                      (w2 * 64 + lane) * 8);
            tot[0] += bf2f(p[0]); tot[1] += bf2f(p[1]);
            tot[2] += bf2f(p[2]); tot[3] += bf2f(p[3]);
        }
        f32x4 ex;                           // no max-shift: |score| ~ O(1)
        ex[0] = __expf(tot[0]); ex[1] = __expf(tot[1]);
        ex[2] = __expf(tot[2]); ex[3] = __expf(tot[3]);
        *(u16x4*)(smem + WT_OFF + wv * 512 + c16 * 32 + g * 8) = pk4v(ex);
        if (wv == (tt & 7)) {               // attn store, rotated across waves
            float* ap = attn_e + ((size_t)b * HH + c16) * LL + l0 + tt * 16 + g * 4;
            *(float4*)ap = make_float4(ex[0], ex[1], ex[2], ex[3]);
        }
        s_acc += ex[0] + ex[1] + ex[2] + ex[3];
        // ---- stage tile tt+1 into buf[(tt+1)&1] (own strip), issue tt+2 ----
        if (tt < NT - 1) {
            char* wb = smem + ((tt + 1) & 1) * 32768;
#pragma unroll
            for (int j = 0; j < 8; ++j)
                *(u16x4*)(wb + wr_base + j * 512) = pk4(raw[j]);
            if (tt < NT - 2) {
                const float* gs = gbase + (size_t)(tt + 2) * 16 * DD;
#pragma unroll
                for (int j = 0; j < 8; ++j)
                    raw[j] = *(const float4*)(gs + 16 * j);
            }
        }
#if HAVE_MFMA16
        // ---- PV(tt) k=16 on buf[tt&1]: A = wt, B = 1 tr_read per n-tile ----
        {
            bf16x4 afrag;
            u16x4 aw = *(const u16x4*)(smem + WT_OFF + wv * 512 + c16 * 32 + g * 8);
            afrag[0] = (short)aw[0]; afrag[1] = (short)aw[1];
            afrag[2] = (short)aw[2]; afrag[3] = (short)aw[3];
            u32x2 q[8];
#pragma unroll
            for (int nt = 0; nt < 8; ++nt) {
                const int est = wv * 8 + nt;
                const unsigned ta = (unsigned)((tt & 1) * 32768 + est * 512 +
                                               g * 128 + c16 * 8);
                asm volatile("ds_read_b64_tr_b16 %0, %1"
                             : "=v"(q[nt]) : "v"(ta));
            }
            asm volatile("s_waitcnt lgkmcnt(0)" ::: "memory");
            __builtin_amdgcn_sched_barrier(0);
#pragma unroll
            for (int nt = 0; nt < 8; ++nt) {
                union { unsigned u[2]; bf16x4 v; } bb;
                bb.u[0] = q[nt][0]; bb.u[1] = q[nt][1];
                pv[nt] = MFMA16(afrag, bb.v, pv[nt]);
            }
        }
#else
        // ---- PV(tt) fallback: k=32 with zero-padded A ----
        {
            bf16x8 afrag;
            if (g < 2) {
                afrag = *(const bf16x8*)(smem + WT_OFF + wv * 512 + c16 * 32 + g * 16);
            } else {
                afrag = (bf16x8){0, 0, 0, 0, 0, 0, 0, 0};
            }
#pragma unroll
            for (int grp = 0; grp < 2; ++grp) {
                u32x2 q[8];
#pragma unroll
                for (int n2 = 0; n2 < 4; ++n2) {
                    const int est = wv * 8 + grp * 4 + n2;
                    const unsigned ta = (unsigned)((tt & 1) * 32768 + est * 512 +
                                                   (g & 1) * 256 + c16 * 8);
                    asm volatile("ds_read_b64_tr_b16 %0, %1"
                                 : "=v"(q[n2 * 2]) : "v"(ta));
                    asm volatile("ds_read_b64_tr_b16 %0, %1 offset:128"
                                 : "=v"(q[n2 * 2 + 1]) : "v"(ta));
                }
                asm volatile("s_waitcnt lgkmcnt(0)" ::: "memory");
                __builtin_amdgcn_sched_barrier(0);
#pragma unroll
                for (int n2 = 0; n2 < 4; ++n2) {
                    union { unsigned u[4]; bf16x8 v; } bb;
                    bb.u[0] = q[n2 * 2][0];     bb.u[1] = q[n2 * 2][1];
                    bb.u[2] = q[n2 * 2 + 1][0]; bb.u[3] = q[n2 * 2 + 1][1];
                    pv[grp * 4 + n2] = MFMA(afrag, bb.v, pv[grp * 4 + n2]);
                }
            }
        }
#endif
        // ---- scores(tt+1) on buf[(tt+1)&1] -> red[(tt+1)&1] ----
        if (tt < NT - 1) {
            const char* rb = smem + ((tt + 1) & 1) * 32768;
            f32x4 sa = {0.f, 0.f, 0.f, 0.f};
#pragma unroll
            for (int ks = 0; ks < 4; ++ks) {
                const int e16 = wv * 8 + ks * 2 + (g >> 1);
                const int byt = (e16 * 4 + (c16 >> 2)) * 128 + (c16 & 3) * 32 + (g & 1) * 16;
                bf16x8 a = *(const bf16x8*)(rb + byt);
                sa = MFMA(a, rpk[ks], sa);
            }
            *(u16x4*)(smem + RED_OFF + ((tt + 1) & 1) * 4096 +
                      (wv * 64 + lane) * 8) = pk4v(sa);
        }
        __syncthreads();                    // red[(tt+1)&1] visible; red[tt&1] free
    }
    // ---- epilogue: ssum + partials (bf16) ----
    float sv = s_acc;                       // identical in all waves
    sv += __shfl_xor(sv, 16, 64);
    sv += __shfl_xor(sv, 32, 64);
    if (wv == 0 && lane < 16)
        ssum[((size_t)b * NCK + ck) * HH + c16] = sv;
    unsigned short* pp = part + ((size_t)b * NCK + ck) * (HH * DD);
#pragma unroll
    for (int nt = 0; nt < 8; ++nt) {
#pragma unroll
        for (int r2 = 0; r2 < 4; ++r2)
            pp[(size_t)(g * 4 + r2) * DD + estrip + nt * 16 + c16] = f2bf(pv[nt][r2]);
    }
}

// ---------------- combine + attn-normalize + Wv: ctx[b, h*64+j] ------------
__global__ void k_ctx(const float* __restrict__ ipw, const float* __restrict__ ipb,
                      const unsigned short* __restrict__ part,
                      const float* __restrict__ ssum,
                      float* __restrict__ attn_e, float* __restrict__ ctx) {
    const int bh = blockIdx.x, b = bh >> 4, h = bh & 15;   // 512 blocks
    const int t = threadIdx.x, w = t >> 6, lane = t & 63;  // 256
    float S = 0.f;
#pragma unroll
    for (int c = 0; c < NCK; ++c) S += ssum[((size_t)b * NCK + c) * HH + h];
    const float inv = 1.0f / S;
    float4* ar = (float4*)(attn_e + (size_t)bh * LL);
#pragma unroll
    for (int i = 0; i < 2; ++i) {
        float4 v = ar[t + 256 * i];
        v.x *= inv; v.y *= inv; v.z *= inv; v.w *= inv;
        ar[t + 256 * i] = v;
    }
    __shared__ float Xl[DD];
    float4 x = {0.f, 0.f, 0.f, 0.f};
#pragma unroll
    for (int c = 0; c < NCK; ++c) {
        u16x4 p = *(const u16x4*)(part + ((size_t)b * NCK + c) * (HH * DD) +
                                  (size_t)h * DD + t * 4);
        x.x += bf2f(p[0]); x.y += bf2f(p[1]);
        x.z += bf2f(p[2]); x.w += bf2f(p[3]);
    }
    float4 xs = {x.x * inv, x.y * inv, x.z * inv, x.w * inv};
    ((float4*)Xl)[t] = xs;
    __syncthreads();
    for (int jj = 0; jj < 16; ++jj) {
        const int j = w * 16 + jj;
        const float* row = ipw + (size_t)(2 * DD + h * DHH + j) * DD;
        float acc = 0.f;
#pragma unroll
        for (int it = 0; it < 4; ++it) {
            float4 a = ((const float4*)row)[lane + 64 * it];
            float4 p = ((const float4*)Xl)[lane + 64 * it];
            acc += a.x * p.x + a.y * p.y + a.z * p.z + a.w * p.w;
        }
        acc = wave_sum(acc);
        if (lane == 0) ctx[(size_t)b * DD + h * DHH + j] = acc + ipb[2 * DD + h * DHH + j];
    }
}

// ---------------- y[b, d'] = out_w[d',:]·ctx[b,:] + out_b ----------------
__global__ void k_y(const float* __restrict__ ow, const float* __restrict__ ob,
                    const float* __restrict__ ctx, float* __restrict__ y) {
    const int blk = blockIdx.x, b = blk >> 4, ch = blk & 15;  // 512 blocks
    const int t = threadIdx.x, w = t >> 6, lane = t & 63;     // 256
    __shared__ float Xl[DD];
    ((float4*)Xl)[t] = ((const float4*)(ctx + (size_t)b * DD))[t];
    __syncthreads();
    for (int jj = 0; jj < 16; ++jj) {
        const int d = ch * 64 + w * 16 + jj;
        const float* row = ow + (size_t)d * DD;
        float acc = 0.f;
#pragma unroll
        for (int it = 0; it < 4; ++it) {
            float4 a = ((const float4*)row)[lane + 64 * it];
            float4 p = ((const float4*)Xl)[lane + 64 * it];
            acc += a.x * p.x + a.y * p.y + a.z * p.z + a.w * p.w;
        }
        acc = wave_sum(acc);
        if (lane == 0) y[(size_t)b * DD + d] = acc + ob[d];
    }
}

// ---------------- final LN -> pooled output ----------------
__global__ void k_lnout(const float* __restrict__ y, const float* __restrict__ on_w,
                        const float* __restrict__ on_b, float* __restrict__ outp) {
    const int b = blockIdx.x, t = threadIdx.x;   // 32 blocks, 256 threads
    const float4 x = ((const float4*)(y + (size_t)b * DD))[t];
    float s  = x.x + x.y + x.z + x.w;
    float s2 = x.x * x.x + x.y * x.y + x.z * x.z + x.w * x.w;
    __shared__ float rs[4], rs2[4];
    s = wave_sum(s); s2 = wave_sum(s2);
    const int w = t >> 6, lane = t & 63;
    if (lane == 0) { rs[w] = s; rs2[w] = s2; }
    __syncthreads();
    s  = rs[0] + rs[1] + rs[2] + rs[3];
    s2 = rs2[0] + rs2[1] + rs2[2] + rs2[3];
    const float mu  = s * (1.0f / DD);
    const float var = s2 * (1.0f / DD) - mu * mu;
    const float rstd = rsqrtf(var + 1e-5f);
    const float4 w4 = ((const float4*)on_w)[t];
    const float4 b4 = ((const float4*)on_b)[t];
    float4 o;
    o.x = (x.x - mu) * rstd * w4.x + b4.x;
    o.y = (x.y - mu) * rstd * w4.y + b4.y;
    o.z = (x.z - mu) * rstd * w4.z + b4.z;
    o.w = (x.w - mu) * rstd * w4.w + b4.w;
    ((float4*)(outp + (size_t)b * DD))[t] = o;
}

extern "C" void kernel_launch(void* const* d_in, const int* in_sizes, int n_in,
                              void* d_out, int out_size, void* d_ws, size_t ws_size,
                              hipStream_t stream) {
    const float* gr   = (const float*)d_in[0];
    const float* sq   = (const float*)d_in[1];
    const float* qn_w = (const float*)d_in[2];
    const float* qn_b = (const float*)d_in[3];
    const float* ipw  = (const float*)d_in[4];
    const float* ipb  = (const float*)d_in[5];
    const float* ow   = (const float*)d_in[6];
    const float* ob   = (const float*)d_in[7];
    const float* on_w = (const float*)d_in[8];
    const float* on_b = (const float*)d_in[9];
    const int*   pos  = (const int*)d_in[10];

    float* out  = (float*)d_out;
    float* attn = out + BB * DD;           // output 1; holds exp(score) until k_ctx norms
    float* ws   = (float*)d_ws;
    unsigned short* part16 = (unsigned short*)(ws + WS_PART);

    hipFuncSetAttribute((const void*)k_fused,
                        hipFuncAttributeMaxDynamicSharedMemorySize, SMEM_BYTES);

    k_q<<<256, 256, 0, stream>>>(sq, qn_w, qn_b, pos, ipw, ipb, ws);
    k_r<<<256, 64, 0, stream>>>(ipw, ipb, ws);
    k_fused<<<BB * NCK, 512, SMEM_BYTES, stream>>>(gr, ws, attn,
                                                   part16, ws + WS_SSUM);
    k_ctx<<<BB * HH, 256, 0, stream>>>(ipw, ipb, part16, ws + WS_SSUM,
                                       attn, ws + WS_CTX);
    k_y<<<BB * 16, 256, 0, stream>>>(ow, ob, ws + WS_CTX, ws + WS_Y);
    k_lnout<<<BB, 256, 0, stream>>>(ws + WS_Y, on_w, on_b, out);
}

// Round 17
// 99.494 us; speedup vs baseline: 1.0888x; 1.0020x over previous
//
#include <hip/hip_runtime.h>
#include <hip/hip_bf16.h>
#include <math.h>

#define BB 32
#define LL 2048
#define DD 1024
#define HH 16
#define DHH 64
#define NCK 16         // chunks per batch
#define CH  128        // rows per chunk
#define NT  8          // 16-row tiles per chunk

// ---- ws layout (float offsets) ----
#define WS_Q     1024       // 1024
#define WS_R     2048       // 16*1024
#define WS_C     18432      // 64 (16 used)
#define WS_CTX   19008      // 32768
#define WS_Y     51776      // 32768
#define WS_SSUM  84544      // 32*16*16 = 8192
#define WS_PART  92736      // 32*16*16*1024 bf16 = 16 MB

// ---- k_fused dynamic LDS layout (bytes) ----
// G tile buffers: 2 x (16 rows x 1024 e bf16, [4 l][16 e]-subtiled) = 2x32768
//   byte(l,e) = (e>>4)*512 + (l>>2)*128 + (l&3)*32 + (e&15)*2
//   buf regions are WAVE-PRIVATE (wave wv owns e16 in [wv*8, wv*8+8))
// red: 2 x (8 waves x 64 lanes x u16x4 bf16) = 2 x 4096  (double-buffered)
#define RED_OFF  65536
#define WT_OFF   73728      // 8 waves x 16 h x 16 l bf16 = 4096
#define SMEM_BYTES 77824

typedef __attribute__((ext_vector_type(8))) short    bf16x8;
typedef __attribute__((ext_vector_type(4))) short    bf16x4;
typedef __attribute__((ext_vector_type(4))) float    f32x4;
typedef __attribute__((ext_vector_type(2))) unsigned u32x2;
typedef __attribute__((ext_vector_type(4))) unsigned short u16x4;
typedef __attribute__((ext_vector_type(8))) unsigned short u16x8;

#define MFMA(a, b, c) __builtin_amdgcn_mfma_f32_16x16x32_bf16(a, b, c, 0, 0, 0)

#if defined(__has_builtin)
#if __has_builtin(__builtin_amdgcn_mfma_f32_16x16x16bf16_1k)
#define HAVE_MFMA16 1
#define MFMA16(a, b, c) __builtin_amdgcn_mfma_f32_16x16x16bf16_1k(a, b, c, 0, 0, 0)
#endif
#endif
#ifndef HAVE_MFMA16
#define HAVE_MFMA16 0
#endif

__device__ __forceinline__ unsigned short f2bf(float f) {   // RNE f32->bf16
    unsigned u = __float_as_uint(f);
    return (unsigned short)((u + 0x7FFFu + ((u >> 16) & 1u)) >> 16);
}
// hot-path pack: v_cvt_pk_bf16_f32 via builtin (same RNE as f2bf)
__device__ __forceinline__ u16x4 pk4(float4 f) {
    __hip_bfloat162 a = __float22bfloat162_rn(make_float2(f.x, f.y));
    __hip_bfloat162 b = __float22bfloat162_rn(make_float2(f.z, f.w));
    ushort2 ua = *reinterpret_cast<ushort2*>(&a);
    ushort2 ub = *reinterpret_cast<ushort2*>(&b);
    u16x4 r; r[0] = ua.x; r[1] = ua.y; r[2] = ub.x; r[3] = ub.y;
    return r;
}
__device__ __forceinline__ u16x4 pk4v(f32x4 f) {
    return pk4(make_float4(f[0], f[1], f[2], f[3]));
}
__device__ __forceinline__ float bf2f(unsigned short u) {
    return __uint_as_float((unsigned)u << 16);
}
__device__ __forceinline__ float wave_sum(float v) {
#pragma unroll
    for (int s = 32; s >= 1; s >>= 1) v += __shfl_xor(v, s, 64);
    return v;
}

// ---------------- K1: q = Wq @ LN(sq[pos]) + bq  (LN fused, wave/output) ----
__global__ void k_q(const float* __restrict__ sq, const float* __restrict__ qn_w,
                    const float* __restrict__ qn_b, const int* __restrict__ pos,
                    const float* __restrict__ ipw, const float* __restrict__ ipb,
                    float* __restrict__ ws) {
    const int t = threadIdx.x;              // 256 threads
    const int w = t >> 6, lane = t & 63;
    __shared__ float q0s[DD];
    __shared__ float rs[4], rs2[4];
    {   // redundant per-block LN of the single query row (4 KB, L2-hot)
        const float4 x = ((const float4*)(sq + (size_t)pos[0] * DD))[t];
        float s  = x.x + x.y + x.z + x.w;
        float s2 = x.x * x.x + x.y * x.y + x.z * x.z + x.w * x.w;
        s = wave_sum(s); s2 = wave_sum(s2);
        if (lane == 0) { rs[w] = s; rs2[w] = s2; }
        __syncthreads();
        s  = rs[0] + rs[1] + rs[2] + rs[3];
        s2 = rs2[0] + rs2[1] + rs2[2] + rs2[3];
        const float mu  = s * (1.0f / DD);
        const float var = s2 * (1.0f / DD) - mu * mu;
        const float rstd = rsqrtf(var + 1e-5f);
        const float4 w4 = ((const float4*)qn_w)[t];
        const float4 b4 = ((const float4*)qn_b)[t];
        float4 o;
        o.x = (x.x - mu) * rstd * w4.x + b4.x;
        o.y = (x.y - mu) * rstd * w4.y + b4.y;
        o.z = (x.z - mu) * rstd * w4.z + b4.z;
        o.w = (x.w - mu) * rstd * w4.w + b4.w;
        ((float4*)q0s)[t] = o;
    }
    __syncthreads();
    const int d = blockIdx.x * 4 + w;       // 256 blocks * 4 waves = 1024 outputs
    const float* row = ipw + (size_t)d * DD;
    float acc = 0.f;
#pragma unroll
    for (int it = 0; it < 4; ++it) {
        float4 a = ((const float4*)row)[lane + 64 * it];
        float4 b = ((const float4*)q0s)[lane + 64 * it];
        acc += a.x * b.x + a.y * b.y + a.z * b.z + a.w * b.w;
    }
    acc = wave_sum(acc);
    if (lane == 0) (ws + WS_Q)[d] = acc + ipb[d];
}

// ------- K2: r_s[h,e] = scale * sum_j q[h,j] Wk[h*64+j, e]  (256 blocks) ----
__global__ void k_r(const float* __restrict__ ipw, const float* __restrict__ ipb,
                    float* __restrict__ ws) {
    const int h = blockIdx.x >> 4, s = blockIdx.x & 15;
    const int t = threadIdx.x;              // 64 threads
    const int e = s * 64 + t;
    const float* q = ws + WS_Q;
    const float* wk = ipw + (size_t)(DD + h * DHH) * DD;
    float acc = 0.f;
#pragma unroll 8
    for (int j = 0; j < DHH; ++j)
        acc += q[h * DHH + j] * wk[(size_t)j * DD + e];
    (ws + WS_R)[h * DD + e] = acc * 0.125f;
    if (s == 0) {
        float p = q[h * DHH + t] * ipb[DD + h * DHH + t];
        p = wave_sum(p);
        if (t == 0) (ws + WS_C)[h] = p * 0.125f;
    }
}

// ---------------- fused MFMA, wave-local staging, ONE barrier/tile ---------
// block = (b, 128-row chunk), 8 waves (512 thr); 8 tiles of 16 rows.
// Each wave stages ITS OWN e-strip (16 rows x 128 e) -> G buffers are
//   wave-private; stage->scores and PV->overwrite are own-wave lgkm-ordered.
//   Only the cross-wave score reduction `red` needs sync: double-buffered
//   (bf16), 1 barrier/tile.
// Per iter: finish(tt) [red[tt&1]] | stage(tt+1)+issue(tt+2) | PV(tt) |
//           scores(tt+1)->red[(tt+1)&1] | BARRIER.
// R17: partials epilogue coalesced -- pv transposed through the (dead)
//   G-buffer LDS to [16 h][1024 e] bf16, then 4x global_store_dwordx4 per
//   thread (1KB/wave-instr) instead of 32 scalar 2B stores (4x32B segments).
__global__ __launch_bounds__(512, 4)
void k_fused(const float* __restrict__ gr, const float* __restrict__ ws,
             float* __restrict__ attn_e, unsigned short* __restrict__ part,
             float* __restrict__ ssum) {
    extern __shared__ char smem[];
    const int b  = blockIdx.x >> 4;
    const int ck = blockIdx.x & 15;
    const int l0 = ck * CH;
    const int t  = threadIdx.x;
    const int wv = t >> 6, lane = t & 63;
    const int c16 = lane & 15, g = lane >> 4;
    const int estrip = wv * 128;            // this wave's e-strip

    // ---- prologue: pack r into B-frags (4 k-steps x 32 e), bias ----
    bf16x8 rpk[4];
#pragma unroll
    for (int ks = 0; ks < 4; ++ks) {
        const float* rp = ws + WS_R + (size_t)c16 * DD + estrip + ks * 32 + g * 8;
        float4 f0 = *(const float4*)rp, f1 = *(const float4*)(rp + 4);
        u16x4 lo = pk4(f0), hi = pk4(f1);
        bf16x8 r;
        r[0] = (short)lo[0]; r[1] = (short)lo[1]; r[2] = (short)lo[2]; r[3] = (short)lo[3];
        r[4] = (short)hi[0]; r[5] = (short)hi[1]; r[6] = (short)hi[2]; r[7] = (short)hi[3];
        rpk[ks] = r;
    }
    const float myc = (ws + WS_C)[c16];

    f32x4 pv[8];
#pragma unroll
    for (int i = 0; i < 8; ++i) pv[i] = (f32x4){0.f, 0.f, 0.f, 0.f};
    float s_acc = 0.f;

    // ---- wave-local staging geometry ----
    const int srow = (lane >> 4) * 4 + ((lane >> 2) & 3);   // row 0..15
    const float* gbase = gr + ((size_t)(b * LL + l0) + srow) * DD +
                         estrip + (lane & 3) * 4;
    const int wr_base = (wv * 8) * 512 + (lane >> 4) * 128 +
                        ((lane >> 2) & 3) * 32 + (lane & 3) * 8;

    float4 raw[8];
    // tile 0: load + pack + write buf0 (own strip)
#pragma unroll
    for (int j = 0; j < 8; ++j) raw[j] = *(const float4*)(gbase + 16 * j);
#pragma unroll
    for (int j = 0; j < 8; ++j)
        *(u16x4*)(smem + wr_base + j * 512) = pk4(raw[j]);
    // issue tile 1 loads
#pragma unroll
    for (int j = 0; j < 8; ++j)
        raw[j] = *(const float4*)(gbase + 16 * DD + 16 * j);
    // scores(0) -> red[0]   (own-wave lgkm ordering covers stage->read)
    {
        f32x4 sa = {0.f, 0.f, 0.f, 0.f};
#pragma unroll
        for (int ks = 0; ks < 4; ++ks) {
            const int e16 = wv * 8 + ks * 2 + (g >> 1);
            const int byt = (e16 * 4 + (c16 >> 2)) * 128 + (c16 & 3) * 32 + (g & 1) * 16;
            bf16x8 a = *(const bf16x8*)(smem + byt);
            sa = MFMA(a, rpk[ks], sa);
        }
        *(u16x4*)(smem + RED_OFF + (wv * 64 + lane) * 8) = pk4v(sa);
    }
    __syncthreads();

#pragma unroll 1
    for (int tt = 0; tt < NT; ++tt) {
        // ---- finish(tt): sum 8 bf16 wave-partials + bias, exp ----
        f32x4 tot = {myc, myc, myc, myc};
#pragma unroll
        for (int w2 = 0; w2 < 8; ++w2) {
            u16x4 p = *(const u16x4*)(smem + RED_OFF + (tt & 1) * 4096 +
                                      (w2 * 64 + lane) * 8);
            tot[0] += bf2f(p[0]); tot[1] += bf2f(p[1]);
            tot[2] += bf2f(p[2]); tot[3] += bf2f(p[3]);
        }
        f32x4 ex;                           // no max-shift: |score| ~ O(1)
        ex[0] = __expf(tot[0]); ex[1] = __expf(tot[1]);
        ex[2] = __expf(tot[2]); ex[3] = __expf(tot[3]);
        *(u16x4*)(smem + WT_OFF + wv * 512 + c16 * 32 + g * 8) = pk4v(ex);
        if (wv == (tt & 7)) {               // attn store, rotated across waves
            float* ap = attn_e + ((size_t)b * HH + c16) * LL + l0 + tt * 16 + g * 4;
            *(float4*)ap = make_float4(ex[0], ex[1], ex[2], ex[3]);
        }
        s_acc += ex[0] + ex[1] + ex[2] + ex[3];
        // ---- stage tile tt+1 into buf[(tt+1)&1] (own strip), issue tt+2 ----
        if (tt < NT - 1) {
            char* wb = smem + ((tt + 1) & 1) * 32768;
#pragma unroll
            for (int j = 0; j < 8; ++j)
                *(u16x4*)(wb + wr_base + j * 512) = pk4(raw[j]);
            if (tt < NT - 2) {
                const float* gs = gbase + (size_t)(tt + 2) * 16 * DD;
#pragma unroll
                for (int j = 0; j < 8; ++j)
                    raw[j] = *(const float4*)(gs + 16 * j);
            }
        }
#if HAVE_MFMA16
        // ---- PV(tt) k=16 on buf[tt&1]: A = wt, B = 1 tr_read per n-tile ----
        {
            bf16x4 afrag;
            u16x4 aw = *(const u16x4*)(smem + WT_OFF + wv * 512 + c16 * 32 + g * 8);
            afrag[0] = (short)aw[0]; afrag[1] = (short)aw[1];
            afrag[2] = (short)aw[2]; afrag[3] = (short)aw[3];
            u32x2 q[8];
#pragma unroll
            for (int nt = 0; nt < 8; ++nt) {
                const int est = wv * 8 + nt;
                const unsigned ta = (unsigned)((tt & 1) * 32768 + est * 512 +
                                               g * 128 + c16 * 8);
                asm volatile("ds_read_b64_tr_b16 %0, %1"
                             : "=v"(q[nt]) : "v"(ta));
            }
            asm volatile("s_waitcnt lgkmcnt(0)" ::: "memory");
            __builtin_amdgcn_sched_barrier(0);
#pragma unroll
            for (int nt = 0; nt < 8; ++nt) {
                union { unsigned u[2]; bf16x4 v; } bb;
                bb.u[0] = q[nt][0]; bb.u[1] = q[nt][1];
                pv[nt] = MFMA16(afrag, bb.v, pv[nt]);
            }
        }
#else
        // ---- PV(tt) fallback: k=32 with zero-padded A ----
        {
            bf16x8 afrag;
            if (g < 2) {
                afrag = *(const bf16x8*)(smem + WT_OFF + wv * 512 + c16 * 32 + g * 16);
            } else {
                afrag = (bf16x8){0, 0, 0, 0, 0, 0, 0, 0};
            }
#pragma unroll
            for (int grp = 0; grp < 2; ++grp) {
                u32x2 q[8];
#pragma unroll
                for (int n2 = 0; n2 < 4; ++n2) {
                    const int est = wv * 8 + grp * 4 + n2;
                    const unsigned ta = (unsigned)((tt & 1) * 32768 + est * 512 +
                                                   (g & 1) * 256 + c16 * 8);
                    asm volatile("ds_read_b64_tr_b16 %0, %1"
                                 : "=v"(q[n2 * 2]) : "v"(ta));
                    asm volatile("ds_read_b64_tr_b16 %0, %1 offset:128"
                                 : "=v"(q[n2 * 2 + 1]) : "v"(ta));
                }
                asm volatile("s_waitcnt lgkmcnt(0)" ::: "memory");
                __builtin_amdgcn_sched_barrier(0);
#pragma unroll
                for (int n2 = 0; n2 < 4; ++n2) {
                    union { unsigned u[4]; bf16x8 v; } bb;
                    bb.u[0] = q[n2 * 2][0];     bb.u[1] = q[n2 * 2][1];
                    bb.u[2] = q[n2 * 2 + 1][0]; bb.u[3] = q[n2 * 2 + 1][1];
                    pv[grp * 4 + n2] = MFMA(afrag, bb.v, pv[grp * 4 + n2]);
                }
            }
        }
#endif
        // ---- scores(tt+1) on buf[(tt+1)&1] -> red[(tt+1)&1] ----
        if (tt < NT - 1) {
            const char* rb = smem + ((tt + 1) & 1) * 32768;
            f32x4 sa = {0.f, 0.f, 0.f, 0.f};
#pragma unroll
            for (int ks = 0; ks < 4; ++ks) {
                const int e16 = wv * 8 + ks * 2 + (g >> 1);
                const int byt = (e16 * 4 + (c16 >> 2)) * 128 + (c16 & 3) * 32 + (g & 1) * 16;
                bf16x8 a = *(const bf16x8*)(rb + byt);
                sa = MFMA(a, rpk[ks], sa);
            }
            *(u16x4*)(smem + RED_OFF + ((tt + 1) & 1) * 4096 +
                      (wv * 64 + lane) * 8) = pk4v(sa);
        }
        __syncthreads();                    // red[(tt+1)&1] visible; red[tt&1] free
    }
    // ---- epilogue: ssum + COALESCED partials via LDS transpose (R17) ----
    float sv = s_acc;                       // identical in all waves
    sv += __shfl_xor(sv, 16, 64);
    sv += __shfl_xor(sv, 32, 64);
    if (wv == 0 && lane < 16)
        ssum[((size_t)b * NCK + ck) * HH + c16] = sv;
    // All waves passed the loop's final barrier -> G buffers dead. Transpose
    // pv into smem[0..32KB) as [16 h][1024 e] bf16.
    {
        unsigned short* tb = (unsigned short*)smem;
#pragma unroll
        for (int nt = 0; nt < 8; ++nt)
#pragma unroll
            for (int r2 = 0; r2 < 4; ++r2)
                tb[(g * 4 + r2) * DD + estrip + nt * 16 + c16] = f2bf(pv[nt][r2]);
    }
    __syncthreads();
    {   // thread t stores a contiguous 64B run: 4 x global_store_dwordx4
        const unsigned short* tb = (const unsigned short*)smem;
        unsigned short* pp = part + ((size_t)b * NCK + ck) * (HH * DD) + t * 32;
#pragma unroll
        for (int i = 0; i < 4; ++i)
            *(u16x8*)(pp + i * 8) = *(const u16x8*)(tb + t * 32 + i * 8);
    }
}

// ---------------- combine + attn-normalize + Wv: ctx[b, h*64+j] ------------
__global__ void k_ctx(const float* __restrict__ ipw, const float* __restrict__ ipb,
                      const unsigned short* __restrict__ part,
                      const float* __restrict__ ssum,
                      float* __restrict__ attn_e, float* __restrict__ ctx) {
    const int bh = blockIdx.x, b = bh >> 4, h = bh & 15;   // 512 blocks
    const int t = threadIdx.x, w = t >> 6, lane = t & 63;  // 256
    float S = 0.f;
#pragma unroll
    for (int c = 0; c < NCK; ++c) S += ssum[((size_t)b * NCK + c) * HH + h];
    const float inv = 1.0f / S;
    float4* ar = (float4*)(attn_e + (size_t)bh * LL);
#pragma unroll
    for (int i = 0; i < 2; ++i) {
        float4 v = ar[t + 256 * i];
        v.x *= inv; v.y *= inv; v.z *= inv; v.w *= inv;
        ar[t + 256 * i] = v;
    }
    __shared__ float Xl[DD];
    float4 x = {0.f, 0.f, 0.f, 0.f};
#pragma unroll
    for (int c = 0; c < NCK; ++c) {
        u16x4 p = *(const u16x4*)(part + ((size_t)b * NCK + c) * (HH * DD) +
                                  (size_t)h * DD + t * 4);
        x.x += bf2f(p[0]); x.y += bf2f(p[1]);
        x.z += bf2f(p[2]); x.w += bf2f(p[3]);
    }
    float4 xs = {x.x * inv, x.y * inv, x.z * inv, x.w * inv};
    ((float4*)Xl)[t] = xs;
    __syncthreads();
    for (int jj = 0; jj < 16; ++jj) {
        const int j = w * 16 + jj;
        const float* row = ipw + (size_t)(2 * DD + h * DHH + j) * DD;
        float acc = 0.f;
#pragma unroll
        for (int it = 0; it < 4; ++it) {
            float4 a = ((const float4*)row)[lane + 64 * it];
            float4 p = ((const float4*)Xl)[lane + 64 * it];
            acc += a.x * p.x + a.y * p.y + a.z * p.z + a.w * p.w;
        }
        acc = wave_sum(acc);
        if (lane == 0) ctx[(size_t)b * DD + h * DHH + j] = acc + ipb[2 * DD + h * DHH + j];
    }
}

// ---------------- y[b, d'] = out_w[d',:]·ctx[b,:] + out_b ----------------
__global__ void k_y(const float* __restrict__ ow, const float* __restrict__ ob,
                    const float* __restrict__ ctx, float* __restrict__ y) {
    const int blk = blockIdx.x, b = blk >> 4, ch = blk & 15;  // 512 blocks
    const int t = threadIdx.x, w = t >> 6, lane = t & 63;     // 256
    __shared__ float Xl[DD];
    ((float4*)Xl)[t] = ((const float4*)(ctx + (size_t)b * DD))[t];
    __syncthreads();
    for (int jj = 0; jj < 16; ++jj) {
        const int d = ch * 64 + w * 16 + jj;
        const float* row = ow + (size_t)d * DD;
        float acc = 0.f;
#pragma unroll
        for (int it = 0; it < 4; ++it) {
            float4 a = ((const float4*)row)[lane + 64 * it];
            float4 p = ((const float4*)Xl)[lane + 64 * it];
            acc += a.x * p.x + a.y * p.y + a.z * p.z + a.w * p.w;
        }
        acc = wave_sum(acc);
        if (lane == 0) y[(size_t)b * DD + d] = acc + ob[d];
    }
}

// ---------------- final LN -> pooled output ----------------
__global__ void k_lnout(const float* __restrict__ y, const float* __restrict__ on_w,
                        const float* __restrict__ on_b, float* __restrict__ outp) {
    const int b = blockIdx.x, t = threadIdx.x;   // 32 blocks, 256 threads
    const float4 x = ((const float4*)(y + (size_t)b * DD))[t];
    float s  = x.x + x.y + x.z + x.w;
    float s2 = x.x * x.x + x.y * x.y + x.z * x.z + x.w * x.w;
    __shared__ float rs[4], rs2[4];
    s = wave_sum(s); s2 = wave_sum(s2);
    const int w = t >> 6, lane = t & 63;
    if (lane == 0) { rs[w] = s; rs2[w] = s2; }
    __syncthreads();
    s  = rs[0] + rs[1] + rs[2] + rs[3];
    s2 = rs2[0] + rs2[1] + rs2[2] + rs2[3];
    const float mu  = s * (1.0f / DD);
    const float var = s2 * (1.0f / DD) - mu * mu;
    const float rstd = rsqrtf(var + 1e-5f);
    const float4 w4 = ((const float4*)on_w)[t];
    const float4 b4 = ((const float4*)on_b)[t];
    float4 o;
    o.x = (x.x - mu) * rstd * w4.x + b4.x;
    o.y = (x.y - mu) * rstd * w4.y + b4.y;
    o.z = (x.z - mu) * rstd * w4.z + b4.z;
    o.w = (x.w - mu) * rstd * w4.w + b4.w;
    ((float4*)(outp + (size_t)b * DD))[t] = o;
}

extern "C" void kernel_launch(void* const* d_in, const int* in_sizes, int n_in,
                              void* d_out, int out_size, void* d_ws, size_t ws_size,
                              hipStream_t stream) {
    const float* gr   = (const float*)d_in[0];
    const float* sq   = (const float*)d_in[1];
    const float* qn_w = (const float*)d_in[2];
    const float* qn_b = (const float*)d_in[3];
    const float* ipw  = (const float*)d_in[4];
    const float* ipb  = (const float*)d_in[5];
    const float* ow   = (const float*)d_in[6];
    const float* ob   = (const float*)d_in[7];
    const float* on_w = (const float*)d_in[8];
    const float* on_b = (const float*)d_in[9];
    const int*   pos  = (const int*)d_in[10];

    float* out  = (float*)d_out;
    float* attn = out + BB * DD;           // output 1; holds exp(score) until k_ctx norms
    float* ws   = (float*)d_ws;
    unsigned short* part16 = (unsigned short*)(ws + WS_PART);

    hipFuncSetAttribute((const void*)k_fused,
                        hipFuncAttributeMaxDynamicSharedMemorySize, SMEM_BYTES);

    k_q<<<256, 256, 0, stream>>>(sq, qn_w, qn_b, pos, ipw, ipb, ws);
    k_r<<<256, 64, 0, stream>>>(ipw, ipb, ws);
    k_fused<<<BB * NCK, 512, SMEM_BYTES, stream>>>(gr, ws, attn,
                                                   part16, ws + WS_SSUM);
    k_ctx<<<BB * HH, 256, 0, stream>>>(ipw, ipb, part16, ws + WS_SSUM,
                                       attn, ws + WS_CTX);
    k_y<<<BB * 16, 256, 0, stream>>>(ow, ob, ws + WS_CTX, ws + WS_Y);
    k_lnout<<<BB, 256, 0, stream>>>(ws + WS_Y, on_w, on_b, out);
}